// Round 5
// baseline (801.194 us; speedup 1.0000x reference)
//
#include <hip/hip_runtime.h>
#include <hip/hip_bf16.h>
#include <math.h>

#define LAYERS 4
#define DMODEL 512
#define NH 8
#define DH 64
#define DFF 2048
#define NB 4
#define S_LEN 2048
#define MROWS 8192
#define CHUNK 64
#define NCHUNK 32            // S_LEN / CHUNK
#define ATT_EPS 1e-6f
#define LN_EPS 1e-5f
#define SEGSTRIDE (MROWS * DMODEL)   // 4194304 elems per q/k/v segment

typedef __attribute__((ext_vector_type(8))) short short8v;   // 8 bf16
typedef __attribute__((ext_vector_type(4))) float f32x4;

__device__ __forceinline__ float b2f(unsigned short u) {
    union { float f; unsigned u; } c; c.u = ((unsigned)u) << 16; return c.f;
}
__device__ __forceinline__ unsigned short f2b(float f) {
    union { float f; unsigned u; } c; c.f = f;
    unsigned r = c.u + 0x7FFFu + ((c.u >> 16) & 1u);
    return (unsigned short)(r >> 16);
}
__device__ __forceinline__ void gload16(const void* g, void* l) {
    __builtin_amdgcn_global_load_lds(
        (const __attribute__((address_space(1))) void*)g,
        (__attribute__((address_space(3))) void*)l, 16, 0, 0);
}
__device__ __forceinline__ float elu1f(float v) {
    return (v > 0.f) ? (v + 1.f) : __expf(v);
}
__device__ __forceinline__ float geluf(float v) {
    float u = 0.7978845608028654f * v * (1.f + 0.044715f * v * v);
    float th = 1.f - 2.f / (1.f + __expf(2.f * u));
    return 0.5f * v * (1.f + th);
}

// ---------------------------------------------------------------------------
// bf16 MFMA GEMM: 128x128 tile, BK=32, 4 waves.
// Depth-2 prefetch: 3 LDS buffers, counted s_waitcnt vmcnt (never 0 mid-loop),
// raw s_barrier (no compiler vmcnt(0) drain). T4 from the technique catalog.
// ---------------------------------------------------------------------------
template <int ACT, bool ACCUM, bool WF32, bool WBF16>
__global__ __launch_bounds__(256) void gemm_bf16(
    const unsigned short* __restrict__ A,
    const unsigned short* __restrict__ WT,
    const float* __restrict__ b0, const float* __restrict__ b1,
    const float* __restrict__ b2,
    float* __restrict__ C32, unsigned short* __restrict__ Cbf,
    int M, int N, int K)
{
    __shared__ short As[3][4096];
    __shared__ short Bs[3][4096];

    const int t = threadIdx.x;
    const int m0 = blockIdx.x * 128, n0 = blockIdx.y * 128;
    const int lane = t & 63, wid = t >> 6;
    const int wm = (wid >> 1) * 64, wn = (wid & 1) * 64;
    const int fr = lane & 15, kg = lane >> 4;

    const int srow = t >> 2;
    const int ssw  = (srow & 3) ^ ((srow >> 2) & 3);
    const int sk   = ((t & 3) ^ ssw) * 8;

    const int rsw  = (fr & 3) ^ ((fr >> 2) & 3);
    const int kgs  = (kg ^ rsw) * 8;

    const unsigned short* Ar0 = A + (size_t)(m0 + srow) * K + sk;
    const unsigned short* Ar1 = A + (size_t)(m0 + srow + 64) * K + sk;
    const unsigned short* Br0 = WT + (size_t)(n0 + srow) * K + sk;
    const unsigned short* Br1 = WT + (size_t)(n0 + srow + 64) * K + sk;

    f32x4 acc[4][4];
#pragma unroll
    for (int m = 0; m < 4; ++m)
#pragma unroll
        for (int n = 0; n < 4; ++n) acc[m][n] = (f32x4){0.f, 0.f, 0.f, 0.f};

#define STAGE(buf, kk) do {                              \
    gload16(Ar0 + (kk), &As[buf][t * 8]);                \
    gload16(Ar1 + (kk), &As[buf][t * 8 + 2048]);         \
    gload16(Br0 + (kk), &Bs[buf][t * 8]);                \
    gload16(Br1 + (kk), &Bs[buf][t * 8 + 2048]); } while (0)

    const int NT = K >> 5;
    // prologue: prefetch tiles 0 and 1
    STAGE(0, 0);
    STAGE(1, 32);

    int cur = 0;
    for (int td = 0; td < NT; ++td) {
        // stage tile td+2 (depth-2 prefetch), then wait for tile td's loads only
        if (td + 2 < NT) {
            const int nb = (cur + 2 >= 3) ? (cur - 1) : (cur + 2);
            STAGE(nb, (td + 2) * 32);
            asm volatile("s_waitcnt vmcnt(8)" ::: "memory");
        } else if (td + 1 < NT) {
            asm volatile("s_waitcnt vmcnt(4)" ::: "memory");
        } else {
            asm volatile("s_waitcnt vmcnt(0)" ::: "memory");
        }
        __builtin_amdgcn_s_barrier();   // tile td now visible to all waves

        short8v a[4], b[4];
#pragma unroll
        for (int m = 0; m < 4; ++m)
            a[m] = *(const short8v*)&As[cur][(wm + m * 16 + fr) * 32 + kgs];
#pragma unroll
        for (int n = 0; n < 4; ++n)
            b[n] = *(const short8v*)&Bs[cur][(wn + n * 16 + fr) * 32 + kgs];
#pragma unroll
        for (int m = 0; m < 4; ++m)
#pragma unroll
            for (int n = 0; n < 4; ++n)
                acc[m][n] = __builtin_amdgcn_mfma_f32_16x16x32_bf16(
                    a[m], b[n], acc[m][n], 0, 0, 0);

        // all my ds_reads of buf `cur` complete, then align waves: next
        // iteration's STAGE may overwrite buf `cur`.
        asm volatile("s_waitcnt lgkmcnt(0)" ::: "memory");
        __builtin_amdgcn_s_barrier();
        cur = (cur + 1 >= 3) ? 0 : (cur + 1);
    }
#undef STAGE

    const int seg = (ACT == 3) ? (n0 >> 9) : 0;
    const float* bias = (ACT == 3) ? (seg == 0 ? b0 : (seg == 1 ? b1 : b2)) : b0;
    float bv[4];
#pragma unroll
    for (int n = 0; n < 4; ++n) {
        const int col = n0 + wn + n * 16 + fr;
        bv[n] = bias[(ACT == 3) ? (col - seg * 512) : col];
    }

#pragma unroll
    for (int m = 0; m < 4; ++m)
#pragma unroll
        for (int n = 0; n < 4; ++n)
#pragma unroll
            for (int j = 0; j < 4; ++j) {
                const int row = m0 + wm + m * 16 + (lane >> 4) * 4 + j;
                const int col = n0 + wn + n * 16 + fr;
                float v = acc[m][n][j] + bv[n];
                if (ACCUM) v += C32[(size_t)row * N + col];
                if (ACT == 1) v = elu1f(v);
                else if (ACT == 2) v = geluf(v);
                else if (ACT == 3) { if (seg < 2) v = elu1f(v); }
                if (WF32) C32[(size_t)row * N + col] = v;
                if (WBF16) {
                    if (ACT == 3)
                        Cbf[(size_t)seg * SEGSTRIDE + (size_t)row * 512 + (col - seg * 512)] = f2b(v);
                    else
                        Cbf[(size_t)row * N + col] = f2b(v);
                }
            }
}

// ---------------------------------------------------------------------------
// Weight transpose + bf16
// ---------------------------------------------------------------------------
__global__ __launch_bounds__(256) void transpose_to_bf16(
    const float* __restrict__ W, unsigned short* __restrict__ WT, int K, int N)
{
    __shared__ float tile[32][33];
    const int k0 = blockIdx.x * 32, n0 = blockIdx.y * 32;
    const int tx = threadIdx.x & 31, ty = threadIdx.x >> 5;
#pragma unroll
    for (int i = ty; i < 32; i += 8)
        tile[i][tx] = W[(size_t)(k0 + i) * N + n0 + tx];
    __syncthreads();
#pragma unroll
    for (int i = ty; i < 32; i += 8)
        WT[(size_t)(n0 + i) * K + k0 + tx] = f2b(tile[tx][i]);
}

__global__ __launch_bounds__(256) void cvt_in(
    const float* __restrict__ h, float* __restrict__ x,
    unsigned short* __restrict__ xb, int n)
{
    const int i = (blockIdx.x * 256 + threadIdx.x) * 8;
    if (i >= n) return;
    f32x4 a = *(const f32x4*)(h + i);
    f32x4 b = *(const f32x4*)(h + i + 4);
    *(f32x4*)(x + i) = a;
    *(f32x4*)(x + i + 4) = b;
    short8v p;
    p[0] = f2b(a[0]); p[1] = f2b(a[1]); p[2] = f2b(a[2]); p[3] = f2b(a[3]);
    p[4] = f2b(b[0]); p[5] = f2b(b[1]); p[6] = f2b(b[2]); p[7] = f2b(b[3]);
    *(short8v*)(xb + i) = p;
}

// swizzled 64x64 bf16 tile access: logical (row, sl) -> shorts offset
__device__ __forceinline__ int swzo(int row, int sl) {
    return row * 64 + ((sl ^ (row & 7)) << 3);
}

// ---------------------------------------------------------------------------
// Attention stage 1 (MFMA): per (b,h,chunk) KVt[e][d] = sum_j V[j][e]*K[j][d]
// (bf16 out), z[d] = sum_j K[j][d] (f32).
// ---------------------------------------------------------------------------
__global__ __launch_bounds__(256) void attn_stage1(
    const unsigned short* __restrict__ Kf, const unsigned short* __restrict__ Vf,
    unsigned short* __restrict__ KVp, float* __restrict__ zp)
{
    const int c = blockIdx.x, hh = blockIdx.y, bb = blockIdx.z;
    const int t = threadIdx.x;
    const int lane = t & 63, w = t >> 6;
    const int fr = lane & 15, g = lane >> 4;

    __shared__ unsigned short KTs[64 * 72];   // K^T [d][j], pad 72
    __shared__ unsigned short VTs[64 * 72];   // V^T [e][j], pad 72

    const size_t rowbase = (size_t)(bb * S_LEN + c * CHUNK);
    const int colbase = hh * DH;

    {
        const int r = lane, cs = w * 16;
        const unsigned short* kp = Kf + (rowbase + r) * DMODEL + colbase + cs;
        const unsigned short* vp = Vf + (rowbase + r) * DMODEL + colbase + cs;
        short8v k0 = *(const short8v*)kp, k1 = *(const short8v*)(kp + 8);
        short8v v0 = *(const short8v*)vp, v1 = *(const short8v*)(vp + 8);
#pragma unroll
        for (int i = 0; i < 8; ++i) {
            KTs[(cs + i) * 72 + r]     = (unsigned short)k0[i];
            KTs[(cs + 8 + i) * 72 + r] = (unsigned short)k1[i];
            VTs[(cs + i) * 72 + r]     = (unsigned short)v0[i];
            VTs[(cs + 8 + i) * 72 + r] = (unsigned short)v1[i];
        }
    }
    __syncthreads();

    f32x4 cacc[4];
#pragma unroll
    for (int nf = 0; nf < 4; ++nf) cacc[nf] = (f32x4){0.f, 0.f, 0.f, 0.f};

    const short8v a0 = *(const short8v*)&VTs[(w * 16 + fr) * 72 + g * 8];
    const short8v a1 = *(const short8v*)&VTs[(w * 16 + fr) * 72 + (4 + g) * 8];
#pragma unroll
    for (int nf = 0; nf < 4; ++nf) {
        short8v bq0 = *(const short8v*)&KTs[(nf * 16 + fr) * 72 + g * 8];
        short8v bq1 = *(const short8v*)&KTs[(nf * 16 + fr) * 72 + (4 + g) * 8];
        cacc[nf] = __builtin_amdgcn_mfma_f32_16x16x32_bf16(a0, bq0, cacc[nf], 0, 0, 0);
        cacc[nf] = __builtin_amdgcn_mfma_f32_16x16x32_bf16(a1, bq1, cacc[nf], 0, 0, 0);
    }

    const size_t base = ((size_t)(bb * NH + hh) * NCHUNK + c) * (DH * DH);
#pragma unroll
    for (int nf = 0; nf < 4; ++nf)
#pragma unroll
        for (int reg = 0; reg < 4; ++reg) {
            const int e = w * 16 + g * 4 + reg;
            const int d = nf * 16 + fr;
            KVp[base + e * 64 + d] = f2b(cacc[nf][reg]);
        }

    if (t < 64) {
        float s = 0.f;
#pragma unroll
        for (int sl = 0; sl < 8; ++sl) {
            short8v kv = *(const short8v*)&KTs[t * 72 + sl * 8];
#pragma unroll
            for (int i = 0; i < 8; ++i) s += b2f((unsigned short)kv[i]);
        }
        zp[((size_t)(bb * NH + hh) * NCHUNK + c) * DH + t] = s;
    }
}

// ---------------------------------------------------------------------------
// Attention stage 2: exclusive prefix over 32 chunk states per (b,h)
// ---------------------------------------------------------------------------
__global__ __launch_bounds__(256) void attn_stage2(
    const unsigned short* __restrict__ KVp, unsigned short* __restrict__ KVb,
    float* __restrict__ zp)
{
    const int bh = blockIdx.x;
    const int e = blockIdx.y * 256 + threadIdx.x;
    const size_t base = (size_t)bh * NCHUNK * (DH * DH) + e;
    float run = 0.f;
#pragma unroll 4
    for (int c = 0; c < NCHUNK; ++c) {
        const float tmp = b2f(KVp[base + (size_t)c * (DH * DH)]);
        KVb[base + (size_t)c * (DH * DH)] = f2b(run);
        run += tmp;
    }
    if (blockIdx.y == 0 && threadIdx.x < DH) {
        float rz = 0.f;
        const size_t zb = (size_t)bh * NCHUNK * DH + threadIdx.x;
#pragma unroll 4
        for (int c = 0; c < NCHUNK; ++c) {
            const float tmp = zp[zb + c * DH];
            zp[zb + c * DH] = rz;
            rz += tmp;
        }
    }
}

// ---------------------------------------------------------------------------
// Attention stage 3 (MFMA): per (b,h,chunk of 64):
//  S^T = K Q^T  -> mask j<=i lane-locally -> P (bf16, LDS), den_intra via shfl
//  O = Q KVt_pre^T + P V ;  out = O / (q.z_pre + den_intra + eps)
// ---------------------------------------------------------------------------
__global__ __launch_bounds__(256) void attn_stage3(
    const unsigned short* __restrict__ Qf, const unsigned short* __restrict__ Kf,
    const unsigned short* __restrict__ Vf, const unsigned short* __restrict__ KVb,
    const float* __restrict__ zp, unsigned short* __restrict__ Af)
{
    const int c = blockIdx.x, hh = blockIdx.y, bb = blockIdx.z;
    const int t = threadIdx.x;
    const int lane = t & 63, w = t >> 6;
    const int fr = lane & 15, g = lane >> 4;

    __shared__ unsigned short Qs[4096];
    __shared__ unsigned short Ks[4096];
    __shared__ unsigned short KVts[4096];
    __shared__ unsigned short VTs[64 * 72];
    __shared__ unsigned short Ps[64 * 72];
    __shared__ float zsh[DH];
    __shared__ float den_lds[64];

    const size_t rowbase = (size_t)(bb * S_LEN + c * CHUNK);
    const int colbase = hh * DH;
    const size_t kvbase = ((size_t)(bb * NH + hh) * NCHUNK + c) * (DH * DH);

#pragma unroll
    for (int iss = 0; iss < 2; ++iss) {
        const int u = iss * 256 + t, row = u >> 3, sl = u & 7;
        const int ssl = (sl ^ (row & 7)) * 8;
        gload16(Qf + (rowbase + row) * DMODEL + colbase + ssl, &Qs[(size_t)u * 8]);
        gload16(Kf + (rowbase + row) * DMODEL + colbase + ssl, &Ks[(size_t)u * 8]);
        gload16(KVb + kvbase + row * 64 + ssl, &KVts[(size_t)u * 8]);
    }
    {
        const int r = lane, cs = w * 16;
        const unsigned short* vp = Vf + (rowbase + r) * DMODEL + colbase + cs;
        short8v v0 = *(const short8v*)vp, v1 = *(const short8v*)(vp + 8);
#pragma unroll
        for (int i = 0; i < 8; ++i) {
            VTs[(cs + i) * 72 + r]     = (unsigned short)v0[i];
            VTs[(cs + 8 + i) * 72 + r] = (unsigned short)v1[i];
        }
    }
    if (t < DH) zsh[t] = zp[((size_t)(bb * NH + hh) * NCHUNK + c) * DH + t];
    __syncthreads();

    f32x4 c1[4];
#pragma unroll
    for (int mf = 0; mf < 4; ++mf) c1[mf] = (f32x4){0.f, 0.f, 0.f, 0.f};
    {
        const short8v bq0 = *(const short8v*)&Qs[swzo(w * 16 + fr, g)];
        const short8v bq1 = *(const short8v*)&Qs[swzo(w * 16 + fr, 4 + g)];
#pragma unroll
        for (int mf = 0; mf < 4; ++mf) {
            short8v ak0 = *(const short8v*)&Ks[swzo(mf * 16 + fr, g)];
            short8v ak1 = *(const short8v*)&Ks[swzo(mf * 16 + fr, 4 + g)];
            c1[mf] = __builtin_amdgcn_mfma_f32_16x16x32_bf16(ak0, bq0, c1[mf], 0, 0, 0);
            c1[mf] = __builtin_amdgcn_mfma_f32_16x16x32_bf16(ak1, bq1, c1[mf], 0, 0, 0);
        }
    }

    const int i_my = w * 16 + fr;
    float dint = 0.f;
#pragma unroll
    for (int mf = 0; mf < 4; ++mf)
#pragma unroll
        for (int reg = 0; reg < 4; ++reg) {
            const int j = mf * 16 + g * 4 + reg;
            const float v = (j <= i_my) ? c1[mf][reg] : 0.f;
            dint += v;
            Ps[i_my * 72 + j] = f2b(v);
        }
    dint += __shfl_xor(dint, 16);
    dint += __shfl_xor(dint, 32);

    float dpre = 0.f;
#pragma unroll
    for (int sl = 0; sl < 8; ++sl) {
        short8v qv = *(const short8v*)&Qs[swzo(i_my, sl)];
#pragma unroll
        for (int e = 0; e < 8; ++e) dpre += b2f((unsigned short)qv[e]) * zsh[sl * 8 + e];
    }
    if (g == 0) den_lds[i_my] = dpre + dint + ATT_EPS;

    f32x4 acc[4];
#pragma unroll
    for (int nf = 0; nf < 4; ++nf) acc[nf] = (f32x4){0.f, 0.f, 0.f, 0.f};
    {
        const short8v aq0 = *(const short8v*)&Qs[swzo(w * 16 + fr, g)];
        const short8v aq1 = *(const short8v*)&Qs[swzo(w * 16 + fr, 4 + g)];
#pragma unroll
        for (int nf = 0; nf < 4; ++nf) {
            short8v bkv0 = *(const short8v*)&KVts[swzo(nf * 16 + fr, g)];
            short8v bkv1 = *(const short8v*)&KVts[swzo(nf * 16 + fr, 4 + g)];
            acc[nf] = __builtin_amdgcn_mfma_f32_16x16x32_bf16(aq0, bkv0, acc[nf], 0, 0, 0);
            acc[nf] = __builtin_amdgcn_mfma_f32_16x16x32_bf16(aq1, bkv1, acc[nf], 0, 0, 0);
        }
        const short8v ap0 = *(const short8v*)&Ps[(w * 16 + fr) * 72 + g * 8];
        const short8v ap1 = *(const short8v*)&Ps[(w * 16 + fr) * 72 + (4 + g) * 8];
#pragma unroll
        for (int nf = 0; nf < 4; ++nf) {
            short8v bv0 = *(const short8v*)&VTs[(nf * 16 + fr) * 72 + g * 8];
            short8v bv1 = *(const short8v*)&VTs[(nf * 16 + fr) * 72 + (4 + g) * 8];
            acc[nf] = __builtin_amdgcn_mfma_f32_16x16x32_bf16(ap0, bv0, acc[nf], 0, 0, 0);
            acc[nf] = __builtin_amdgcn_mfma_f32_16x16x32_bf16(ap1, bv1, acc[nf], 0, 0, 0);
        }
    }

#pragma unroll
    for (int reg = 0; reg < 4; ++reg) {
        const int i = w * 16 + g * 4 + reg;
        const float inv = 1.f / den_lds[i];
        unsigned short* dst = Af + (rowbase + i) * DMODEL + colbase;
#pragma unroll
        for (int nf = 0; nf < 4; ++nf)
            dst[nf * 16 + fr] = f2b(acc[nf][reg] * inv);
    }
}

// ---------------------------------------------------------------------------
// LayerNorm over 512: 4 rows per block (one wave each), in-place; bf16 copy.
// ---------------------------------------------------------------------------
__global__ __launch_bounds__(256) void ln_kernel(float* __restrict__ X,
                                                 const float* __restrict__ g,
                                                 const float* __restrict__ b,
                                                 unsigned short* __restrict__ Xb)
{
    const size_t row = blockIdx.x * 4 + (threadIdx.x >> 6);
    const int t = threadIdx.x & 63;
    float* xr = X + row * DMODEL;
    f32x4 x0 = *(const f32x4*)&xr[t * 4];
    f32x4 x1 = *(const f32x4*)&xr[256 + t * 4];

    float s  = x0[0] + x0[1] + x0[2] + x0[3] + x1[0] + x1[1] + x1[2] + x1[3];
    float sq = x0[0]*x0[0] + x0[1]*x0[1] + x0[2]*x0[2] + x0[3]*x0[3] +
               x1[0]*x1[0] + x1[1]*x1[1] + x1[2]*x1[2] + x1[3]*x1[3];
#pragma unroll
    for (int m = 1; m < 64; m <<= 1) {
        s  += __shfl_xor(s, m);
        sq += __shfl_xor(sq, m);
    }
    const float mu  = s * (1.f / DMODEL);
    const float var = sq * (1.f / DMODEL) - mu * mu;
    const float rr  = rsqrtf(var + LN_EPS);

    const int c0 = t * 4, c1 = 256 + t * 4;
    f32x4 g0 = *(const f32x4*)&g[c0], g1v = *(const f32x4*)&g[c1];
    f32x4 b0 = *(const f32x4*)&b[c0], b1v = *(const f32x4*)&b[c1];
    f32x4 y0, y1;
#pragma unroll
    for (int i = 0; i < 4; ++i) {
        y0[i] = (x0[i] - mu) * rr * g0[i] + b0[i];
        y1[i] = (x1[i] - mu) * rr * g1v[i] + b1v[i];
    }
    *(f32x4*)&xr[c0] = y0;
    *(f32x4*)&xr[c1] = y1;
    if (Xb) {
        unsigned short* xb = Xb + row * DMODEL;
        ushort4 u0, u1;
        u0.x = f2b(y0[0]); u0.y = f2b(y0[1]); u0.z = f2b(y0[2]); u0.w = f2b(y0[3]);
        u1.x = f2b(y1[0]); u1.y = f2b(y1[1]); u1.z = f2b(y1[2]); u1.w = f2b(y1[3]);
        *(ushort4*)&xb[c0] = u0;
        *(ushort4*)&xb[c1] = u1;
    }
}

// ---------------------------------------------------------------------------
extern "C" void kernel_launch(void* const* d_in, const int* in_sizes, int n_in,
                              void* d_out, int out_size, void* d_ws, size_t ws_size,
                              hipStream_t stream)
{
    const float* h   = (const float*)d_in[0];
    const float* Wq  = (const float*)d_in[1];
    const float* bq  = (const float*)d_in[2];
    const float* Wk  = (const float*)d_in[3];
    const float* bk  = (const float*)d_in[4];
    const float* Wv  = (const float*)d_in[5];
    const float* bv  = (const float*)d_in[6];
    const float* Wo  = (const float*)d_in[7];
    const float* bo  = (const float*)d_in[8];
    const float* W1  = (const float*)d_in[9];
    const float* b1  = (const float*)d_in[10];
    const float* W2  = (const float*)d_in[11];
    const float* b2  = (const float*)d_in[12];
    const float* g1  = (const float*)d_in[13];
    const float* be1 = (const float*)d_in[14];
    const float* g2  = (const float*)d_in[15];
    const float* be2 = (const float*)d_in[16];
    const float* gf  = (const float*)d_in[17];
    const float* bef = (const float*)d_in[18];

    float* x = (float*)d_out;                     // running activation f32 [8192,512]
    char* ws = (char*)d_ws;
    const size_t MB = 1024 * 1024;
    unsigned short* x_bf = (unsigned short*)(ws);                 // 8 MB
    unsigned short* qkv  = (unsigned short*)(ws + 8 * MB);        // q|k|v 24 MB
    unsigned short* qb   = qkv;
    unsigned short* kb   = qkv + SEGSTRIDE;
    unsigned short* vb   = qkv + 2 * (size_t)SEGSTRIDE;
    unsigned short* ab   = (unsigned short*)(ws + 32 * MB);       // 8 MB
    unsigned short* hid  = (unsigned short*)(ws + 8 * MB);        // 32 MB alias q|k|v|a
    unsigned short* KVp  = (unsigned short*)(ws + 40 * MB);       // partials bf16 8 MB
    unsigned short* KVb  = (unsigned short*)(ws + 48 * MB);       // prefix states 8 MB
    float* zp            = (float*)(ws + 56 * MB);                // 0.5 MB
    unsigned short* WTall = (unsigned short*)(ws + 57 * MB);      // 24 MB

    const int M = MROWS, D = DMODEL, DF = DFF;
    const size_t LSTR = 3 * 1024 * 1024;

    cvt_in<<<dim3(M * D / (256 * 8)), 256, 0, stream>>>(h, x, x_bf, M * D);
    for (int l = 0; l < LAYERS; ++l) {
        unsigned short* WL = WTall + (size_t)l * LSTR;
        transpose_to_bf16<<<dim3(D / 32, D / 32), 256, 0, stream>>>(Wq + (size_t)l * D * D, WL, D, D);
        transpose_to_bf16<<<dim3(D / 32, D / 32), 256, 0, stream>>>(Wk + (size_t)l * D * D, WL + 262144, D, D);
        transpose_to_bf16<<<dim3(D / 32, D / 32), 256, 0, stream>>>(Wv + (size_t)l * D * D, WL + 524288, D, D);
        transpose_to_bf16<<<dim3(D / 32, D / 32), 256, 0, stream>>>(Wo + (size_t)l * D * D, WL + 786432, D, D);
        transpose_to_bf16<<<dim3(D / 32, DF / 32), 256, 0, stream>>>(W1 + (size_t)l * D * DF, WL + 1048576, D, DF);
        transpose_to_bf16<<<dim3(DF / 32, D / 32), 256, 0, stream>>>(W2 + (size_t)l * DF * D, WL + 2097152, DF, D);
    }

    for (int l = 0; l < LAYERS; ++l) {
        unsigned short* WL = WTall + (size_t)l * LSTR;
        const unsigned short* WqkvT = WL;            // [1536][512]
        const unsigned short* WoT   = WL + 786432;   // [512][512]
        const unsigned short* W1T   = WL + 1048576;  // [2048][512]
        const unsigned short* W2T   = WL + 2097152;  // [512][2048]

        gemm_bf16<3, false, false, true><<<dim3(M / 128, 1536 / 128), 256, 0, stream>>>(
            x_bf, WqkvT, bq + (size_t)l * D, bk + (size_t)l * D, bv + (size_t)l * D,
            nullptr, qkv, M, 1536, D);

        attn_stage1<<<dim3(NCHUNK, NH, NB), 256, 0, stream>>>(kb, vb, KVp, zp);
        attn_stage2<<<dim3(NB * NH, 16), 256, 0, stream>>>(KVp, KVb, zp);
        attn_stage3<<<dim3(NCHUNK, NH, NB), 256, 0, stream>>>(qb, kb, vb, KVb, zp, ab);

        gemm_bf16<0, true, true, false><<<dim3(M / 128, D / 128), 256, 0, stream>>>(
            ab, WoT, bo + (size_t)l * D, nullptr, nullptr, x, nullptr, M, D, D);
        ln_kernel<<<dim3(M / 4), 256, 0, stream>>>(x, g1 + (size_t)l * D, be1 + (size_t)l * D, x_bf);

        gemm_bf16<2, false, false, true><<<dim3(M / 128, DF / 128), 256, 0, stream>>>(
            x_bf, W1T, b1 + (size_t)l * DF, nullptr, nullptr, nullptr, hid, M, DF, D);
        gemm_bf16<0, true, true, false><<<dim3(M / 128, D / 128), 256, 0, stream>>>(
            hid, W2T, b2 + (size_t)l * D, nullptr, nullptr, x, nullptr, M, D, DF);
        ln_kernel<<<dim3(M / 4), 256, 0, stream>>>(x, g2 + (size_t)l * D, be2 + (size_t)l * D, x_bf);
    }

    ln_kernel<<<dim3(M / 4), 256, 0, stream>>>(x, gf, bef, nullptr);
}

// Round 6
// 776.656 us; speedup vs baseline: 1.0316x; 1.0316x over previous
//
#include <hip/hip_runtime.h>
#include <hip/hip_bf16.h>
#include <math.h>

#define LAYERS 4
#define DMODEL 512
#define NH 8
#define DH 64
#define DFF 2048
#define NB 4
#define S_LEN 2048
#define MROWS 8192
#define CHUNK 64
#define NCHUNK 32            // S_LEN / CHUNK
#define ATT_EPS 1e-6f
#define LN_EPS 1e-5f
#define SEGSTRIDE (MROWS * DMODEL)   // 4194304 elems per q/k/v segment

typedef __attribute__((ext_vector_type(8))) short short8v;   // 8 bf16
typedef __attribute__((ext_vector_type(4))) float f32x4;

__device__ __forceinline__ float b2f(unsigned short u) {
    union { float f; unsigned u; } c; c.u = ((unsigned)u) << 16; return c.f;
}
__device__ __forceinline__ unsigned short f2b(float f) {
    union { float f; unsigned u; } c; c.f = f;
    unsigned r = c.u + 0x7FFFu + ((c.u >> 16) & 1u);
    return (unsigned short)(r >> 16);
}
__device__ __forceinline__ void gload16(const void* g, void* l) {
    __builtin_amdgcn_global_load_lds(
        (const __attribute__((address_space(1))) void*)g,
        (__attribute__((address_space(3))) void*)l, 16, 0, 0);
}
__device__ __forceinline__ float elu1f(float v) {
    return (v > 0.f) ? (v + 1.f) : __expf(v);
}
__device__ __forceinline__ float geluf(float v) {
    float u = 0.7978845608028654f * v * (1.f + 0.044715f * v * v);
    float th = 1.f - 2.f / (1.f + __expf(2.f * u));
    return 0.5f * v * (1.f + th);
}

// ---------------------------------------------------------------------------
// bf16 MFMA GEMM: 128x128 tile, BK=64, 4 waves (2x2), 2 LDS buffers (64 KB).
// m201-style discipline: counted vmcnt(8) (never 0 mid-loop), bare-asm waits,
// sched_barrier(0) fences, setprio around MFMA bursts, both-sides swizzle.
// ---------------------------------------------------------------------------
template <int ACT, bool ACCUM, bool WF32, bool WBF16>
__global__ __launch_bounds__(256) void gemm_bf16(
    const unsigned short* __restrict__ A,
    const unsigned short* __restrict__ WT,
    const float* __restrict__ b0, const float* __restrict__ b1,
    const float* __restrict__ b2,
    float* __restrict__ C32, unsigned short* __restrict__ Cbf,
    int M, int N, int K)
{
    __shared__ short As[2][8192];   // [128 rows][64 k] per buf
    __shared__ short Bs[2][8192];

    const int t = threadIdx.x;
    const int m0 = blockIdx.x * 128, n0 = blockIdx.y * 128;
    const int lane = t & 63, wid = t >> 6;
    const int wm = (wid >> 1) * 64, wn = (wid & 1) * 64;
    const int fr = lane & 15, kg = lane >> 4;

    // staging: round r covers rows r*32+(t>>3); k-slot swizzled by row&7.
    const int grow = t >> 3;                         // 0..31
    const int gswz = ((t & 7) ^ (grow & 7)) * 8;     // shorts
    const unsigned short* Abase = A + (size_t)(m0 + grow) * K + gswz;
    const unsigned short* Bbase = WT + (size_t)(n0 + grow) * K + gswz;
    const size_t rstep = (size_t)32 * K;

    // fragment read k-slot swizzle (row&7 == fr&7 for all frag rows)
    const int s0 = ((kg) ^ (fr & 7)) * 8;        // kk half 0
    const int s1 = ((4 + kg) ^ (fr & 7)) * 8;    // kk half 1

    f32x4 acc[4][4];
#pragma unroll
    for (int m = 0; m < 4; ++m)
#pragma unroll
        for (int n = 0; n < 4; ++n) acc[m][n] = (f32x4){0.f, 0.f, 0.f, 0.f};

#define STAGE(buf, kt) do { const size_t kko = (size_t)(kt) * 64;          \
    gload16(Abase + kko,             &As[buf][t * 8]);                     \
    gload16(Abase + rstep + kko,     &As[buf][2048 + t * 8]);              \
    gload16(Abase + 2 * rstep + kko, &As[buf][4096 + t * 8]);              \
    gload16(Abase + 3 * rstep + kko, &As[buf][6144 + t * 8]);              \
    gload16(Bbase + kko,             &Bs[buf][t * 8]);                     \
    gload16(Bbase + rstep + kko,     &Bs[buf][2048 + t * 8]);              \
    gload16(Bbase + 2 * rstep + kko, &Bs[buf][4096 + t * 8]);              \
    gload16(Bbase + 3 * rstep + kko, &Bs[buf][6144 + t * 8]); } while (0)

    const int NT = K >> 6;
    STAGE(0, 0);

    int cur = 0;
    for (int td = 0; td < NT; ++td) {
        if (td + 1 < NT) {
            STAGE(cur ^ 1, td + 1);
            asm volatile("s_waitcnt vmcnt(8)");
        } else {
            asm volatile("s_waitcnt vmcnt(0)");
        }
        __builtin_amdgcn_sched_barrier(0);
        __builtin_amdgcn_s_barrier();        // tile td's LDS writes visible
        __builtin_amdgcn_sched_barrier(0);

        short8v a0[4], b0r[4], a1[4], b1r[4];
#pragma unroll
        for (int m = 0; m < 4; ++m)
            a0[m] = *(const short8v*)&As[cur][(wm + m * 16 + fr) * 64 + s0];
#pragma unroll
        for (int n = 0; n < 4; ++n)
            b0r[n] = *(const short8v*)&Bs[cur][(wn + n * 16 + fr) * 64 + s0];
#pragma unroll
        for (int m = 0; m < 4; ++m)
            a1[m] = *(const short8v*)&As[cur][(wm + m * 16 + fr) * 64 + s1];
#pragma unroll
        for (int n = 0; n < 4; ++n)
            b1r[n] = *(const short8v*)&Bs[cur][(wn + n * 16 + fr) * 64 + s1];

        asm volatile("s_waitcnt lgkmcnt(8)");   // half-0 frags ready
        __builtin_amdgcn_sched_barrier(0);
        __builtin_amdgcn_s_setprio(1);
#pragma unroll
        for (int m = 0; m < 4; ++m)
#pragma unroll
            for (int n = 0; n < 4; ++n)
                acc[m][n] = __builtin_amdgcn_mfma_f32_16x16x32_bf16(
                    a0[m], b0r[n], acc[m][n], 0, 0, 0);
        __builtin_amdgcn_s_setprio(0);

        asm volatile("s_waitcnt lgkmcnt(0)");   // half-1 frags ready
        __builtin_amdgcn_sched_barrier(0);
        __builtin_amdgcn_s_setprio(1);
#pragma unroll
        for (int m = 0; m < 4; ++m)
#pragma unroll
            for (int n = 0; n < 4; ++n)
                acc[m][n] = __builtin_amdgcn_mfma_f32_16x16x32_bf16(
                    a1[m], b1r[n], acc[m][n], 0, 0, 0);
        __builtin_amdgcn_s_setprio(0);

        __builtin_amdgcn_sched_barrier(0);
        __builtin_amdgcn_s_barrier();        // all waves done reading buf cur
        cur ^= 1;
    }
#undef STAGE

    const int seg = (ACT == 3) ? (n0 >> 9) : 0;
    const float* bias = (ACT == 3) ? (seg == 0 ? b0 : (seg == 1 ? b1 : b2)) : b0;
    float bv[4];
#pragma unroll
    for (int n = 0; n < 4; ++n) {
        const int col = n0 + wn + n * 16 + fr;
        bv[n] = bias[(ACT == 3) ? (col - seg * 512) : col];
    }

#pragma unroll
    for (int m = 0; m < 4; ++m)
#pragma unroll
        for (int n = 0; n < 4; ++n)
#pragma unroll
            for (int j = 0; j < 4; ++j) {
                const int row = m0 + wm + m * 16 + (lane >> 4) * 4 + j;
                const int col = n0 + wn + n * 16 + fr;
                float v = acc[m][n][j] + bv[n];
                if (ACCUM) v += C32[(size_t)row * N + col];
                if (ACT == 1) v = elu1f(v);
                else if (ACT == 2) v = geluf(v);
                else if (ACT == 3) { if (seg < 2) v = elu1f(v); }
                if (WF32) C32[(size_t)row * N + col] = v;
                if (WBF16) {
                    if (ACT == 3)
                        Cbf[(size_t)seg * SEGSTRIDE + (size_t)row * 512 + (col - seg * 512)] = f2b(v);
                    else
                        Cbf[(size_t)row * N + col] = f2b(v);
                }
            }
}

// ---------------------------------------------------------------------------
// Weight transpose + bf16
// ---------------------------------------------------------------------------
__global__ __launch_bounds__(256) void transpose_to_bf16(
    const float* __restrict__ W, unsigned short* __restrict__ WT, int K, int N)
{
    __shared__ float tile[32][33];
    const int k0 = blockIdx.x * 32, n0 = blockIdx.y * 32;
    const int tx = threadIdx.x & 31, ty = threadIdx.x >> 5;
#pragma unroll
    for (int i = ty; i < 32; i += 8)
        tile[i][tx] = W[(size_t)(k0 + i) * N + n0 + tx];
    __syncthreads();
#pragma unroll
    for (int i = ty; i < 32; i += 8)
        WT[(size_t)(n0 + i) * K + k0 + tx] = f2b(tile[tx][i]);
}

__global__ __launch_bounds__(256) void cvt_in(
    const float* __restrict__ h, float* __restrict__ x,
    unsigned short* __restrict__ xb, int n)
{
    const int i = (blockIdx.x * 256 + threadIdx.x) * 8;
    if (i >= n) return;
    f32x4 a = *(const f32x4*)(h + i);
    f32x4 b = *(const f32x4*)(h + i + 4);
    *(f32x4*)(x + i) = a;
    *(f32x4*)(x + i + 4) = b;
    short8v p;
    p[0] = f2b(a[0]); p[1] = f2b(a[1]); p[2] = f2b(a[2]); p[3] = f2b(a[3]);
    p[4] = f2b(b[0]); p[5] = f2b(b[1]); p[6] = f2b(b[2]); p[7] = f2b(b[3]);
    *(short8v*)(xb + i) = p;
}

// swizzled 64x64 bf16 tile access: logical (row, sl) -> shorts offset
__device__ __forceinline__ int swzo(int row, int sl) {
    return row * 64 + ((sl ^ (row & 7)) << 3);
}

// ---------------------------------------------------------------------------
// Attention stage 1 (MFMA): per (b,h,chunk) KVt[e][d] = sum_j V[j][e]*K[j][d]
// ---------------------------------------------------------------------------
__global__ __launch_bounds__(256) void attn_stage1(
    const unsigned short* __restrict__ Kf, const unsigned short* __restrict__ Vf,
    unsigned short* __restrict__ KVp, float* __restrict__ zp)
{
    const int c = blockIdx.x, hh = blockIdx.y, bb = blockIdx.z;
    const int t = threadIdx.x;
    const int lane = t & 63, w = t >> 6;
    const int fr = lane & 15, g = lane >> 4;

    __shared__ unsigned short KTs[64 * 72];
    __shared__ unsigned short VTs[64 * 72];

    const size_t rowbase = (size_t)(bb * S_LEN + c * CHUNK);
    const int colbase = hh * DH;

    {
        const int r = lane, cs = w * 16;
        const unsigned short* kp = Kf + (rowbase + r) * DMODEL + colbase + cs;
        const unsigned short* vp = Vf + (rowbase + r) * DMODEL + colbase + cs;
        short8v k0 = *(const short8v*)kp, k1 = *(const short8v*)(kp + 8);
        short8v v0 = *(const short8v*)vp, v1 = *(const short8v*)(vp + 8);
#pragma unroll
        for (int i = 0; i < 8; ++i) {
            KTs[(cs + i) * 72 + r]     = (unsigned short)k0[i];
            KTs[(cs + 8 + i) * 72 + r] = (unsigned short)k1[i];
            VTs[(cs + i) * 72 + r]     = (unsigned short)v0[i];
            VTs[(cs + 8 + i) * 72 + r] = (unsigned short)v1[i];
        }
    }
    __syncthreads();

    f32x4 cacc[4];
#pragma unroll
    for (int nf = 0; nf < 4; ++nf) cacc[nf] = (f32x4){0.f, 0.f, 0.f, 0.f};

    const short8v a0 = *(const short8v*)&VTs[(w * 16 + fr) * 72 + g * 8];
    const short8v a1 = *(const short8v*)&VTs[(w * 16 + fr) * 72 + (4 + g) * 8];
#pragma unroll
    for (int nf = 0; nf < 4; ++nf) {
        short8v bq0 = *(const short8v*)&KTs[(nf * 16 + fr) * 72 + g * 8];
        short8v bq1 = *(const short8v*)&KTs[(nf * 16 + fr) * 72 + (4 + g) * 8];
        cacc[nf] = __builtin_amdgcn_mfma_f32_16x16x32_bf16(a0, bq0, cacc[nf], 0, 0, 0);
        cacc[nf] = __builtin_amdgcn_mfma_f32_16x16x32_bf16(a1, bq1, cacc[nf], 0, 0, 0);
    }

    const size_t base = ((size_t)(bb * NH + hh) * NCHUNK + c) * (DH * DH);
#pragma unroll
    for (int nf = 0; nf < 4; ++nf)
#pragma unroll
        for (int reg = 0; reg < 4; ++reg) {
            const int e = w * 16 + g * 4 + reg;
            const int d = nf * 16 + fr;
            KVp[base + e * 64 + d] = f2b(cacc[nf][reg]);
        }

    if (t < 64) {
        float s = 0.f;
#pragma unroll
        for (int sl = 0; sl < 8; ++sl) {
            short8v kv = *(const short8v*)&KTs[t * 72 + sl * 8];
#pragma unroll
            for (int i = 0; i < 8; ++i) s += b2f((unsigned short)kv[i]);
        }
        zp[((size_t)(bb * NH + hh) * NCHUNK + c) * DH + t] = s;
    }
}

// ---------------------------------------------------------------------------
// Attention stage 2: exclusive prefix over 32 chunk states per (b,h)
// ---------------------------------------------------------------------------
__global__ __launch_bounds__(256) void attn_stage2(
    const unsigned short* __restrict__ KVp, unsigned short* __restrict__ KVb,
    float* __restrict__ zp)
{
    const int bh = blockIdx.x;
    const int e = blockIdx.y * 256 + threadIdx.x;
    const size_t base = (size_t)bh * NCHUNK * (DH * DH) + e;
    float run = 0.f;
#pragma unroll 4
    for (int c = 0; c < NCHUNK; ++c) {
        const float tmp = b2f(KVp[base + (size_t)c * (DH * DH)]);
        KVb[base + (size_t)c * (DH * DH)] = f2b(run);
        run += tmp;
    }
    if (blockIdx.y == 0 && threadIdx.x < DH) {
        float rz = 0.f;
        const size_t zb = (size_t)bh * NCHUNK * DH + threadIdx.x;
#pragma unroll 4
        for (int c = 0; c < NCHUNK; ++c) {
            const float tmp = zp[zb + c * DH];
            zp[zb + c * DH] = rz;
            rz += tmp;
        }
    }
}

// ---------------------------------------------------------------------------
// Attention stage 3 (MFMA)
// ---------------------------------------------------------------------------
__global__ __launch_bounds__(256) void attn_stage3(
    const unsigned short* __restrict__ Qf, const unsigned short* __restrict__ Kf,
    const unsigned short* __restrict__ Vf, const unsigned short* __restrict__ KVb,
    const float* __restrict__ zp, unsigned short* __restrict__ Af)
{
    const int c = blockIdx.x, hh = blockIdx.y, bb = blockIdx.z;
    const int t = threadIdx.x;
    const int lane = t & 63, w = t >> 6;
    const int fr = lane & 15, g = lane >> 4;

    __shared__ unsigned short Qs[4096];
    __shared__ unsigned short Ks[4096];
    __shared__ unsigned short KVts[4096];
    __shared__ unsigned short VTs[64 * 72];
    __shared__ unsigned short Ps[64 * 72];
    __shared__ float zsh[DH];
    __shared__ float den_lds[64];

    const size_t rowbase = (size_t)(bb * S_LEN + c * CHUNK);
    const int colbase = hh * DH;
    const size_t kvbase = ((size_t)(bb * NH + hh) * NCHUNK + c) * (DH * DH);

#pragma unroll
    for (int iss = 0; iss < 2; ++iss) {
        const int u = iss * 256 + t, row = u >> 3, sl = u & 7;
        const int ssl = (sl ^ (row & 7)) * 8;
        gload16(Qf + (rowbase + row) * DMODEL + colbase + ssl, &Qs[(size_t)u * 8]);
        gload16(Kf + (rowbase + row) * DMODEL + colbase + ssl, &Ks[(size_t)u * 8]);
        gload16(KVb + kvbase + row * 64 + ssl, &KVts[(size_t)u * 8]);
    }
    {
        const int r = lane, cs = w * 16;
        const unsigned short* vp = Vf + (rowbase + r) * DMODEL + colbase + cs;
        short8v v0 = *(const short8v*)vp, v1 = *(const short8v*)(vp + 8);
#pragma unroll
        for (int i = 0; i < 8; ++i) {
            VTs[(cs + i) * 72 + r]     = (unsigned short)v0[i];
            VTs[(cs + 8 + i) * 72 + r] = (unsigned short)v1[i];
        }
    }
    if (t < DH) zsh[t] = zp[((size_t)(bb * NH + hh) * NCHUNK + c) * DH + t];
    __syncthreads();

    f32x4 c1[4];
#pragma unroll
    for (int mf = 0; mf < 4; ++mf) c1[mf] = (f32x4){0.f, 0.f, 0.f, 0.f};
    {
        const short8v bq0 = *(const short8v*)&Qs[swzo(w * 16 + fr, g)];
        const short8v bq1 = *(const short8v*)&Qs[swzo(w * 16 + fr, 4 + g)];
#pragma unroll
        for (int mf = 0; mf < 4; ++mf) {
            short8v ak0 = *(const short8v*)&Ks[swzo(mf * 16 + fr, g)];
            short8v ak1 = *(const short8v*)&Ks[swzo(mf * 16 + fr, 4 + g)];
            c1[mf] = __builtin_amdgcn_mfma_f32_16x16x32_bf16(ak0, bq0, c1[mf], 0, 0, 0);
            c1[mf] = __builtin_amdgcn_mfma_f32_16x16x32_bf16(ak1, bq1, c1[mf], 0, 0, 0);
        }
    }

    const int i_my = w * 16 + fr;
    float dint = 0.f;
#pragma unroll
    for (int mf = 0; mf < 4; ++mf)
#pragma unroll
        for (int reg = 0; reg < 4; ++reg) {
            const int j = mf * 16 + g * 4 + reg;
            const float v = (j <= i_my) ? c1[mf][reg] : 0.f;
            dint += v;
            Ps[i_my * 72 + j] = f2b(v);
        }
    dint += __shfl_xor(dint, 16);
    dint += __shfl_xor(dint, 32);

    float dpre = 0.f;
#pragma unroll
    for (int sl = 0; sl < 8; ++sl) {
        short8v qv = *(const short8v*)&Qs[swzo(i_my, sl)];
#pragma unroll
        for (int e = 0; e < 8; ++e) dpre += b2f((unsigned short)qv[e]) * zsh[sl * 8 + e];
    }
    if (g == 0) den_lds[i_my] = dpre + dint + ATT_EPS;

    f32x4 acc[4];
#pragma unroll
    for (int nf = 0; nf < 4; ++nf) acc[nf] = (f32x4){0.f, 0.f, 0.f, 0.f};
    {
        const short8v aq0 = *(const short8v*)&Qs[swzo(w * 16 + fr, g)];
        const short8v aq1 = *(const short8v*)&Qs[swzo(w * 16 + fr, 4 + g)];
#pragma unroll
        for (int nf = 0; nf < 4; ++nf) {
            short8v bkv0 = *(const short8v*)&KVts[swzo(nf * 16 + fr, g)];
            short8v bkv1 = *(const short8v*)&KVts[swzo(nf * 16 + fr, 4 + g)];
            acc[nf] = __builtin_amdgcn_mfma_f32_16x16x32_bf16(aq0, bkv0, acc[nf], 0, 0, 0);
            acc[nf] = __builtin_amdgcn_mfma_f32_16x16x32_bf16(aq1, bkv1, acc[nf], 0, 0, 0);
        }
        const short8v ap0 = *(const short8v*)&Ps[(w * 16 + fr) * 72 + g * 8];
        const short8v ap1 = *(const short8v*)&Ps[(w * 16 + fr) * 72 + (4 + g) * 8];
#pragma unroll
        for (int nf = 0; nf < 4; ++nf) {
            short8v bv0 = *(const short8v*)&VTs[(nf * 16 + fr) * 72 + g * 8];
            short8v bv1 = *(const short8v*)&VTs[(nf * 16 + fr) * 72 + (4 + g) * 8];
            acc[nf] = __builtin_amdgcn_mfma_f32_16x16x32_bf16(ap0, bv0, acc[nf], 0, 0, 0);
            acc[nf] = __builtin_amdgcn_mfma_f32_16x16x32_bf16(ap1, bv1, acc[nf], 0, 0, 0);
        }
    }

#pragma unroll
    for (int reg = 0; reg < 4; ++reg) {
        const int i = w * 16 + g * 4 + reg;
        const float inv = 1.f / den_lds[i];
        unsigned short* dst = Af + (rowbase + i) * DMODEL + colbase;
#pragma unroll
        for (int nf = 0; nf < 4; ++nf)
            dst[nf * 16 + fr] = f2b(acc[nf][reg] * inv);
    }
}

// ---------------------------------------------------------------------------
// LayerNorm over 512: 4 rows per block (one wave each), in-place; bf16 copy.
// ---------------------------------------------------------------------------
__global__ __launch_bounds__(256) void ln_kernel(float* __restrict__ X,
                                                 const float* __restrict__ g,
                                                 const float* __restrict__ b,
                                                 unsigned short* __restrict__ Xb)
{
    const size_t row = blockIdx.x * 4 + (threadIdx.x >> 6);
    const int t = threadIdx.x & 63;
    float* xr = X + row * DMODEL;
    f32x4 x0 = *(const f32x4*)&xr[t * 4];
    f32x4 x1 = *(const f32x4*)&xr[256 + t * 4];

    float s  = x0[0] + x0[1] + x0[2] + x0[3] + x1[0] + x1[1] + x1[2] + x1[3];
    float sq = x0[0]*x0[0] + x0[1]*x0[1] + x0[2]*x0[2] + x0[3]*x0[3] +
               x1[0]*x1[0] + x1[1]*x1[1] + x1[2]*x1[2] + x1[3]*x1[3];
#pragma unroll
    for (int m = 1; m < 64; m <<= 1) {
        s  += __shfl_xor(s, m);
        sq += __shfl_xor(sq, m);
    }
    const float mu  = s * (1.f / DMODEL);
    const float var = sq * (1.f / DMODEL) - mu * mu;
    const float rr  = rsqrtf(var + LN_EPS);

    const int c0 = t * 4, c1 = 256 + t * 4;
    f32x4 g0 = *(const f32x4*)&g[c0], g1v = *(const f32x4*)&g[c1];
    f32x4 b0 = *(const f32x4*)&b[c0], b1v = *(const f32x4*)&b[c1];
    f32x4 y0, y1;
#pragma unroll
    for (int i = 0; i < 4; ++i) {
        y0[i] = (x0[i] - mu) * rr * g0[i] + b0[i];
        y1[i] = (x1[i] - mu) * rr * g1v[i] + b1v[i];
    }
    *(f32x4*)&xr[c0] = y0;
    *(f32x4*)&xr[c1] = y1;
    if (Xb) {
        unsigned short* xb = Xb + row * DMODEL;
        ushort4 u0, u1;
        u0.x = f2b(y0[0]); u0.y = f2b(y0[1]); u0.z = f2b(y0[2]); u0.w = f2b(y0[3]);
        u1.x = f2b(y1[0]); u1.y = f2b(y1[1]); u1.z = f2b(y1[2]); u1.w = f2b(y1[3]);
        *(ushort4*)&xb[c0] = u0;
        *(ushort4*)&xb[c1] = u1;
    }
}

// ---------------------------------------------------------------------------
extern "C" void kernel_launch(void* const* d_in, const int* in_sizes, int n_in,
                              void* d_out, int out_size, void* d_ws, size_t ws_size,
                              hipStream_t stream)
{
    const float* h   = (const float*)d_in[0];
    const float* Wq  = (const float*)d_in[1];
    const float* bq  = (const float*)d_in[2];
    const float* Wk  = (const float*)d_in[3];
    const float* bk  = (const float*)d_in[4];
    const float* Wv  = (const float*)d_in[5];
    const float* bv  = (const float*)d_in[6];
    const float* Wo  = (const float*)d_in[7];
    const float* bo  = (const float*)d_in[8];
    const float* W1  = (const float*)d_in[9];
    const float* b1  = (const float*)d_in[10];
    const float* W2  = (const float*)d_in[11];
    const float* b2  = (const float*)d_in[12];
    const float* g1  = (const float*)d_in[13];
    const float* be1 = (const float*)d_in[14];
    const float* g2  = (const float*)d_in[15];
    const float* be2 = (const float*)d_in[16];
    const float* gf  = (const float*)d_in[17];
    const float* bef = (const float*)d_in[18];

    float* x = (float*)d_out;                     // running activation f32 [8192,512]
    char* ws = (char*)d_ws;
    const size_t MB = 1024 * 1024;
    unsigned short* x_bf = (unsigned short*)(ws);                 // 8 MB
    unsigned short* qkv  = (unsigned short*)(ws + 8 * MB);        // q|k|v 24 MB
    unsigned short* qb   = qkv;
    unsigned short* kb   = qkv + SEGSTRIDE;
    unsigned short* vb   = qkv + 2 * (size_t)SEGSTRIDE;
    unsigned short* ab   = (unsigned short*)(ws + 32 * MB);       // 8 MB
    unsigned short* hid  = (unsigned short*)(ws + 8 * MB);        // 32 MB alias q|k|v|a
    unsigned short* KVp  = (unsigned short*)(ws + 40 * MB);       // partials bf16 8 MB
    unsigned short* KVb  = (unsigned short*)(ws + 48 * MB);       // prefix states 8 MB
    float* zp            = (float*)(ws + 56 * MB);                // 0.5 MB
    unsigned short* WTall = (unsigned short*)(ws + 57 * MB);      // 24 MB

    const int M = MROWS, D = DMODEL, DF = DFF;
    const size_t LSTR = 3 * 1024 * 1024;

    cvt_in<<<dim3(M * D / (256 * 8)), 256, 0, stream>>>(h, x, x_bf, M * D);
    for (int l = 0; l < LAYERS; ++l) {
        unsigned short* WL = WTall + (size_t)l * LSTR;
        transpose_to_bf16<<<dim3(D / 32, D / 32), 256, 0, stream>>>(Wq + (size_t)l * D * D, WL, D, D);
        transpose_to_bf16<<<dim3(D / 32, D / 32), 256, 0, stream>>>(Wk + (size_t)l * D * D, WL + 262144, D, D);
        transpose_to_bf16<<<dim3(D / 32, D / 32), 256, 0, stream>>>(Wv + (size_t)l * D * D, WL + 524288, D, D);
        transpose_to_bf16<<<dim3(D / 32, D / 32), 256, 0, stream>>>(Wo + (size_t)l * D * D, WL + 786432, D, D);
        transpose_to_bf16<<<dim3(D / 32, DF / 32), 256, 0, stream>>>(W1 + (size_t)l * D * DF, WL + 1048576, D, DF);
        transpose_to_bf16<<<dim3(DF / 32, D / 32), 256, 0, stream>>>(W2 + (size_t)l * DF * D, WL + 2097152, DF, D);
    }

    for (int l = 0; l < LAYERS; ++l) {
        unsigned short* WL = WTall + (size_t)l * LSTR;
        const unsigned short* WqkvT = WL;            // [1536][512]
        const unsigned short* WoT   = WL + 786432;   // [512][512]
        const unsigned short* W1T   = WL + 1048576;  // [2048][512]
        const unsigned short* W2T   = WL + 2097152;  // [512][2048]

        gemm_bf16<3, false, false, true><<<dim3(M / 128, 1536 / 128), 256, 0, stream>>>(
            x_bf, WqkvT, bq + (size_t)l * D, bk + (size_t)l * D, bv + (size_t)l * D,
            nullptr, qkv, M, 1536, D);

        attn_stage1<<<dim3(NCHUNK, NH, NB), 256, 0, stream>>>(kb, vb, KVp, zp);
        attn_stage2<<<dim3(NB * NH, 16), 256, 0, stream>>>(KVp, KVb, zp);
        attn_stage3<<<dim3(NCHUNK, NH, NB), 256, 0, stream>>>(qb, kb, vb, KVb, zp, ab);

        gemm_bf16<0, true, true, false><<<dim3(M / 128, D / 128), 256, 0, stream>>>(
            ab, WoT, bo + (size_t)l * D, nullptr, nullptr, x, nullptr, M, D, D);
        ln_kernel<<<dim3(M / 4), 256, 0, stream>>>(x, g1 + (size_t)l * D, be1 + (size_t)l * D, x_bf);

        gemm_bf16<2, false, false, true><<<dim3(M / 128, DF / 128), 256, 0, stream>>>(
            x_bf, W1T, b1 + (size_t)l * DF, nullptr, nullptr, nullptr, hid, M, DF, D);
        gemm_bf16<0, true, true, false><<<dim3(M / 128, D / 128), 256, 0, stream>>>(
            hid, W2T, b2 + (size_t)l * D, nullptr, nullptr, x, nullptr, M, D, DF);
        ln_kernel<<<dim3(M / 4), 256, 0, stream>>>(x, g2 + (size_t)l * D, be2 + (size_t)l * D, x_bf);
    }

    ln_kernel<<<dim3(M / 4), 256, 0, stream>>>(x, gf, bef, nullptr);
}

// Round 7
// 733.887 us; speedup vs baseline: 1.0917x; 1.0583x over previous
//
#include <hip/hip_runtime.h>
#include <hip/hip_bf16.h>
#include <math.h>

#define LAYERS 4
#define DMODEL 512
#define NH 8
#define DH 64
#define DFF 2048
#define NB 4
#define S_LEN 2048
#define MROWS 8192
#define CHUNK 64
#define NCHUNK 32            // S_LEN / CHUNK
#define ATT_EPS 1e-6f
#define LN_EPS 1e-5f
#define SEGSTRIDE (MROWS * DMODEL)   // 4194304 elems per q/k/v segment

typedef __attribute__((ext_vector_type(8))) short short8v;   // 8 bf16
typedef __attribute__((ext_vector_type(4))) float f32x4;

__device__ __forceinline__ float b2f(unsigned short u) {
    union { float f; unsigned u; } c; c.u = ((unsigned)u) << 16; return c.f;
}
__device__ __forceinline__ unsigned short f2b(float f) {
    union { float f; unsigned u; } c; c.f = f;
    unsigned r = c.u + 0x7FFFu + ((c.u >> 16) & 1u);
    return (unsigned short)(r >> 16);
}
__device__ __forceinline__ void gload16(const void* g, void* l) {
    __builtin_amdgcn_global_load_lds(
        (const __attribute__((address_space(1))) void*)g,
        (__attribute__((address_space(3))) void*)l, 16, 0, 0);
}
__device__ __forceinline__ float elu1f(float v) {
    return (v > 0.f) ? (v + 1.f) : __expf(v);
}
__device__ __forceinline__ float geluf(float v) {
    float u = 0.7978845608028654f * v * (1.f + 0.044715f * v * v);
    float th = 1.f - 2.f / (1.f + __expf(2.f * u));
    return 0.5f * v * (1.f + th);
}

// ---------------------------------------------------------------------------
// bf16 MFMA GEMM, quad-buffered BK=32 pipeline, prefetch depth 3.
// iteration td: STAGE(td+3) -> vmcnt(12) (tile td provably landed, 3 tiles in
// flight) -> barrier -> ds_read frags -> MFMA burst (setprio) -> barrier.
// LDS layout: row-pair swizzle. Logical (row, kslot s) lives at 16B-unit
//   p*8 + (((row&1)*4+s) ^ (p&7)), p = row>>1  -> 2-way reads (free),
// staged linearly by gload_lds from pre-swizzled global source (rule 21).
// ---------------------------------------------------------------------------
template <int BM, int BN, int TH, int WGM, int WGN,
          int ACT, bool ACCUM, bool WF32, bool WBF16>
__global__ __launch_bounds__(TH) void gemm_mfma(
    const unsigned short* __restrict__ A,
    const unsigned short* __restrict__ WT,
    const float* __restrict__ b0, const float* __restrict__ b1,
    const float* __restrict__ b2,
    float* __restrict__ C32, unsigned short* __restrict__ Cbf,
    int M, int N, int K)
{
    constexpr int MREP = BM / WGM / 16;
    constexpr int NREP = BN / WGN / 16;
    constexpr int TILE = (BM + BN) * 32;   // shorts per buffer
    static_assert((BM + BN) * 4 / TH == 4, "4 loads per thread per tile");

    __shared__ short S[4][TILE];

    const int t = threadIdx.x;
    const int m0 = blockIdx.x * BM, n0 = blockIdx.y * BN;
    const int lane = t & 63, wid = t >> 6;
    const int wm = (wid / WGN) * (BM / WGM);
    const int wn = (wid % WGN) * (BN / WGN);
    const int fr = lane & 15, kg = lane >> 4;

    // staging precompute: rounds 0,1 -> A region, rounds 2,3 -> B region
    const unsigned short* gsrc[4];
    int ldso[4];
#pragma unroll
    for (int r = 0; r < 4; ++r) {
        const int u = r * TH + t;
        const bool isA = (r < 2);
        const int u2 = isA ? u : u - BM * 4;
        const int p = u2 >> 3, sl = (u2 & 7) ^ (p & 7);
        const int row = 2 * p + (sl >> 2), kof = (sl & 3) * 8;
        gsrc[r] = (isA ? A + (size_t)(m0 + row) * K
                       : WT + (size_t)(n0 + row) * K) + kof;
        ldso[r] = (isA ? 0 : BM * 32) + u2 * 8;
    }

    // fragment read offsets (shorts, within a buffer)
    int aoff[MREP], boff[NREP];
#pragma unroll
    for (int m = 0; m < MREP; ++m) {
        const int R = wm + m * 16 + fr, p = R >> 1;
        aoff[m] = p * 64 + ((((R & 1) << 2) | kg) ^ (p & 7)) * 8;
    }
#pragma unroll
    for (int n = 0; n < NREP; ++n) {
        const int R = wn + n * 16 + fr, p = R >> 1;
        boff[n] = BM * 32 + p * 64 + ((((R & 1) << 2) | kg) ^ (p & 7)) * 8;
    }

    f32x4 acc[MREP][NREP];
#pragma unroll
    for (int m = 0; m < MREP; ++m)
#pragma unroll
        for (int n = 0; n < NREP; ++n) acc[m][n] = (f32x4){0.f, 0.f, 0.f, 0.f};

#define STAGE(b, kt) do { _Pragma("unroll")                                  \
    for (int r = 0; r < 4; ++r)                                              \
        gload16(gsrc[r] + (size_t)(kt) * 32, &S[b][ldso[r]]); } while (0)

    const int NT = K >> 5;
    STAGE(0, 0);
    STAGE(1, 1);
    STAGE(2, 2);

    for (int td = 0; td < NT; ++td) {
        const int b = td & 3;
        if (td + 3 < NT) {
            STAGE((td + 3) & 3, td + 3);
            __builtin_amdgcn_sched_barrier(0);
            asm volatile("s_waitcnt vmcnt(12)");
        } else {
            const int ah = NT - 1 - td;
            __builtin_amdgcn_sched_barrier(0);
            if (ah == 2)      asm volatile("s_waitcnt vmcnt(8)");
            else if (ah == 1) asm volatile("s_waitcnt vmcnt(4)");
            else              asm volatile("s_waitcnt vmcnt(0)");
        }
        __builtin_amdgcn_sched_barrier(0);
        __builtin_amdgcn_s_barrier();        // tile td visible to all waves
        __builtin_amdgcn_sched_barrier(0);

        short8v af[MREP], bf[NREP];
#pragma unroll
        for (int m = 0; m < MREP; ++m)
            af[m] = *(const short8v*)&S[b][aoff[m]];
#pragma unroll
        for (int n = 0; n < NREP; ++n)
            bf[n] = *(const short8v*)&S[b][boff[n]];

        __builtin_amdgcn_sched_barrier(0);
        asm volatile("s_waitcnt lgkmcnt(0)");
        __builtin_amdgcn_sched_barrier(0);
        __builtin_amdgcn_s_setprio(1);
#pragma unroll
        for (int m = 0; m < MREP; ++m)
#pragma unroll
            for (int n = 0; n < NREP; ++n)
                acc[m][n] = __builtin_amdgcn_mfma_f32_16x16x32_bf16(
                    af[m], bf[n], acc[m][n], 0, 0, 0);
        __builtin_amdgcn_s_setprio(0);
        __builtin_amdgcn_sched_barrier(0);
        __builtin_amdgcn_s_barrier();        // protect buf b before restage
    }
#undef STAGE

    // epilogue
    const int seg = (ACT == 3) ? (n0 >> 9) : 0;
    const float* bias = (ACT == 3) ? (seg == 0 ? b0 : (seg == 1 ? b1 : b2)) : b0;
    float bv[NREP];
#pragma unroll
    for (int n = 0; n < NREP; ++n) {
        const int col = n0 + wn + n * 16 + fr;
        bv[n] = bias[(ACT == 3) ? (col - seg * 512) : col];
    }

#pragma unroll
    for (int m = 0; m < MREP; ++m)
#pragma unroll
        for (int n = 0; n < NREP; ++n)
#pragma unroll
            for (int j = 0; j < 4; ++j) {
                const int row = m0 + wm + m * 16 + (lane >> 4) * 4 + j;
                const int col = n0 + wn + n * 16 + fr;
                float v = acc[m][n][j] + bv[n];
                if (ACCUM) v += C32[(size_t)row * N + col];
                if (ACT == 1) v = elu1f(v);
                else if (ACT == 2) v = geluf(v);
                else if (ACT == 3) { if (seg < 2) v = elu1f(v); }
                if (WF32) C32[(size_t)row * N + col] = v;
                if (WBF16) {
                    if (ACT == 3)
                        Cbf[(size_t)seg * SEGSTRIDE + (size_t)row * 512 + (col - seg * 512)] = f2b(v);
                    else
                        Cbf[(size_t)row * N + col] = f2b(v);
                }
            }
}

// ---------------------------------------------------------------------------
// Weight transpose + bf16
// ---------------------------------------------------------------------------
__global__ __launch_bounds__(256) void transpose_to_bf16(
    const float* __restrict__ W, unsigned short* __restrict__ WT, int K, int N)
{
    __shared__ float tile[32][33];
    const int k0 = blockIdx.x * 32, n0 = blockIdx.y * 32;
    const int tx = threadIdx.x & 31, ty = threadIdx.x >> 5;
#pragma unroll
    for (int i = ty; i < 32; i += 8)
        tile[i][tx] = W[(size_t)(k0 + i) * N + n0 + tx];
    __syncthreads();
#pragma unroll
    for (int i = ty; i < 32; i += 8)
        WT[(size_t)(n0 + i) * K + k0 + tx] = f2b(tile[tx][i]);
}

__global__ __launch_bounds__(256) void cvt_in(
    const float* __restrict__ h, float* __restrict__ x,
    unsigned short* __restrict__ xb, int n)
{
    const int i = (blockIdx.x * 256 + threadIdx.x) * 8;
    if (i >= n) return;
    f32x4 a = *(const f32x4*)(h + i);
    f32x4 b = *(const f32x4*)(h + i + 4);
    *(f32x4*)(x + i) = a;
    *(f32x4*)(x + i + 4) = b;
    short8v p;
    p[0] = f2b(a[0]); p[1] = f2b(a[1]); p[2] = f2b(a[2]); p[3] = f2b(a[3]);
    p[4] = f2b(b[0]); p[5] = f2b(b[1]); p[6] = f2b(b[2]); p[7] = f2b(b[3]);
    *(short8v*)(xb + i) = p;
}

// swizzled 64x64 bf16 tile access: logical (row, sl) -> shorts offset
__device__ __forceinline__ int swzo(int row, int sl) {
    return row * 64 + ((sl ^ (row & 7)) << 3);
}

// ---------------------------------------------------------------------------
// Attention stage 1 (MFMA): per (b,h,chunk) KVt[e][d] = sum_j V[j][e]*K[j][d]
// ---------------------------------------------------------------------------
__global__ __launch_bounds__(256) void attn_stage1(
    const unsigned short* __restrict__ Kf, const unsigned short* __restrict__ Vf,
    unsigned short* __restrict__ KVp, float* __restrict__ zp)
{
    const int c = blockIdx.x, hh = blockIdx.y, bb = blockIdx.z;
    const int t = threadIdx.x;
    const int lane = t & 63, w = t >> 6;
    const int fr = lane & 15, g = lane >> 4;

    __shared__ unsigned short KTs[64 * 72];
    __shared__ unsigned short VTs[64 * 72];

    const size_t rowbase = (size_t)(bb * S_LEN + c * CHUNK);
    const int colbase = hh * DH;

    {
        const int r = lane, cs = w * 16;
        const unsigned short* kp = Kf + (rowbase + r) * DMODEL + colbase + cs;
        const unsigned short* vp = Vf + (rowbase + r) * DMODEL + colbase + cs;
        short8v k0 = *(const short8v*)kp, k1 = *(const short8v*)(kp + 8);
        short8v v0 = *(const short8v*)vp, v1 = *(const short8v*)(vp + 8);
#pragma unroll
        for (int i = 0; i < 8; ++i) {
            KTs[(cs + i) * 72 + r]     = (unsigned short)k0[i];
            KTs[(cs + 8 + i) * 72 + r] = (unsigned short)k1[i];
            VTs[(cs + i) * 72 + r]     = (unsigned short)v0[i];
            VTs[(cs + 8 + i) * 72 + r] = (unsigned short)v1[i];
        }
    }
    __syncthreads();

    f32x4 cacc[4];
#pragma unroll
    for (int nf = 0; nf < 4; ++nf) cacc[nf] = (f32x4){0.f, 0.f, 0.f, 0.f};

    const short8v a0 = *(const short8v*)&VTs[(w * 16 + fr) * 72 + g * 8];
    const short8v a1 = *(const short8v*)&VTs[(w * 16 + fr) * 72 + (4 + g) * 8];
#pragma unroll
    for (int nf = 0; nf < 4; ++nf) {
        short8v bq0 = *(const short8v*)&KTs[(nf * 16 + fr) * 72 + g * 8];
        short8v bq1 = *(const short8v*)&KTs[(nf * 16 + fr) * 72 + (4 + g) * 8];
        cacc[nf] = __builtin_amdgcn_mfma_f32_16x16x32_bf16(a0, bq0, cacc[nf], 0, 0, 0);
        cacc[nf] = __builtin_amdgcn_mfma_f32_16x16x32_bf16(a1, bq1, cacc[nf], 0, 0, 0);
    }

    const size_t base = ((size_t)(bb * NH + hh) * NCHUNK + c) * (DH * DH);
#pragma unroll
    for (int nf = 0; nf < 4; ++nf)
#pragma unroll
        for (int reg = 0; reg < 4; ++reg) {
            const int e = w * 16 + g * 4 + reg;
            const int d = nf * 16 + fr;
            KVp[base + e * 64 + d] = f2b(cacc[nf][reg]);
        }

    if (t < 64) {
        float s = 0.f;
#pragma unroll
        for (int sl = 0; sl < 8; ++sl) {
            short8v kv = *(const short8v*)&KTs[t * 72 + sl * 8];
#pragma unroll
            for (int i = 0; i < 8; ++i) s += b2f((unsigned short)kv[i]);
        }
        zp[((size_t)(bb * NH + hh) * NCHUNK + c) * DH + t] = s;
    }
}

// ---------------------------------------------------------------------------
// Attention stage 2: exclusive prefix over 32 chunk states per (b,h)
// ---------------------------------------------------------------------------
__global__ __launch_bounds__(256) void attn_stage2(
    const unsigned short* __restrict__ KVp, unsigned short* __restrict__ KVb,
    float* __restrict__ zp)
{
    const int bh = blockIdx.x;
    const int e = blockIdx.y * 256 + threadIdx.x;
    const size_t base = (size_t)bh * NCHUNK * (DH * DH) + e;
    float run = 0.f;
#pragma unroll 4
    for (int c = 0; c < NCHUNK; ++c) {
        const float tmp = b2f(KVp[base + (size_t)c * (DH * DH)]);
        KVb[base + (size_t)c * (DH * DH)] = f2b(run);
        run += tmp;
    }
    if (blockIdx.y == 0 && threadIdx.x < DH) {
        float rz = 0.f;
        const size_t zb = (size_t)bh * NCHUNK * DH + threadIdx.x;
#pragma unroll 4
        for (int c = 0; c < NCHUNK; ++c) {
            const float tmp = zp[zb + c * DH];
            zp[zb + c * DH] = rz;
            rz += tmp;
        }
    }
}

// ---------------------------------------------------------------------------
// Attention stage 3 (MFMA)
// ---------------------------------------------------------------------------
__global__ __launch_bounds__(256) void attn_stage3(
    const unsigned short* __restrict__ Qf, const unsigned short* __restrict__ Kf,
    const unsigned short* __restrict__ Vf, const unsigned short* __restrict__ KVb,
    const float* __restrict__ zp, unsigned short* __restrict__ Af)
{
    const int c = blockIdx.x, hh = blockIdx.y, bb = blockIdx.z;
    const int t = threadIdx.x;
    const int lane = t & 63, w = t >> 6;
    const int fr = lane & 15, g = lane >> 4;

    __shared__ unsigned short Qs[4096];
    __shared__ unsigned short Ks[4096];
    __shared__ unsigned short KVts[4096];
    __shared__ unsigned short VTs[64 * 72];
    __shared__ unsigned short Ps[64 * 72];
    __shared__ float zsh[DH];
    __shared__ float den_lds[64];

    const size_t rowbase = (size_t)(bb * S_LEN + c * CHUNK);
    const int colbase = hh * DH;
    const size_t kvbase = ((size_t)(bb * NH + hh) * NCHUNK + c) * (DH * DH);

#pragma unroll
    for (int iss = 0; iss < 2; ++iss) {
        const int u = iss * 256 + t, row = u >> 3, sl = u & 7;
        const int ssl = (sl ^ (row & 7)) * 8;
        gload16(Qf + (rowbase + row) * DMODEL + colbase + ssl, &Qs[(size_t)u * 8]);
        gload16(Kf + (rowbase + row) * DMODEL + colbase + ssl, &Ks[(size_t)u * 8]);
        gload16(KVb + kvbase + row * 64 + ssl, &KVts[(size_t)u * 8]);
    }
    {
        const int r = lane, cs = w * 16;
        const unsigned short* vp = Vf + (rowbase + r) * DMODEL + colbase + cs;
        short8v v0 = *(const short8v*)vp, v1 = *(const short8v*)(vp + 8);
#pragma unroll
        for (int i = 0; i < 8; ++i) {
            VTs[(cs + i) * 72 + r]     = (unsigned short)v0[i];
            VTs[(cs + 8 + i) * 72 + r] = (unsigned short)v1[i];
        }
    }
    if (t < DH) zsh[t] = zp[((size_t)(bb * NH + hh) * NCHUNK + c) * DH + t];
    __syncthreads();

    f32x4 c1[4];
#pragma unroll
    for (int mf = 0; mf < 4; ++mf) c1[mf] = (f32x4){0.f, 0.f, 0.f, 0.f};
    {
        const short8v bq0 = *(const short8v*)&Qs[swzo(w * 16 + fr, g)];
        const short8v bq1 = *(const short8v*)&Qs[swzo(w * 16 + fr, 4 + g)];
#pragma unroll
        for (int mf = 0; mf < 4; ++mf) {
            short8v ak0 = *(const short8v*)&Ks[swzo(mf * 16 + fr, g)];
            short8v ak1 = *(const short8v*)&Ks[swzo(mf * 16 + fr, 4 + g)];
            c1[mf] = __builtin_amdgcn_mfma_f32_16x16x32_bf16(ak0, bq0, c1[mf], 0, 0, 0);
            c1[mf] = __builtin_amdgcn_mfma_f32_16x16x32_bf16(ak1, bq1, c1[mf], 0, 0, 0);
        }
    }

    const int i_my = w * 16 + fr;
    float dint = 0.f;
#pragma unroll
    for (int mf = 0; mf < 4; ++mf)
#pragma unroll
        for (int reg = 0; reg < 4; ++reg) {
            const int j = mf * 16 + g * 4 + reg;
            const float v = (j <= i_my) ? c1[mf][reg] : 0.f;
            dint += v;
            Ps[i_my * 72 + j] = f2b(v);
        }
    dint += __shfl_xor(dint, 16);
    dint += __shfl_xor(dint, 32);

    float dpre = 0.f;
#pragma unroll
    for (int sl = 0; sl < 8; ++sl) {
        short8v qv = *(const short8v*)&Qs[swzo(i_my, sl)];
#pragma unroll
        for (int e = 0; e < 8; ++e) dpre += b2f((unsigned short)qv[e]) * zsh[sl * 8 + e];
    }
    if (g == 0) den_lds[i_my] = dpre + dint + ATT_EPS;

    f32x4 acc[4];
#pragma unroll
    for (int nf = 0; nf < 4; ++nf) acc[nf] = (f32x4){0.f, 0.f, 0.f, 0.f};
    {
        const short8v aq0 = *(const short8v*)&Qs[swzo(w * 16 + fr, g)];
        const short8v aq1 = *(const short8v*)&Qs[swzo(w * 16 + fr, 4 + g)];
#pragma unroll
        for (int nf = 0; nf < 4; ++nf) {
            short8v bkv0 = *(const short8v*)&KVts[swzo(nf * 16 + fr, g)];
            short8v bkv1 = *(const short8v*)&KVts[swzo(nf * 16 + fr, 4 + g)];
            acc[nf] = __builtin_amdgcn_mfma_f32_16x16x32_bf16(aq0, bkv0, acc[nf], 0, 0, 0);
            acc[nf] = __builtin_amdgcn_mfma_f32_16x16x32_bf16(aq1, bkv1, acc[nf], 0, 0, 0);
        }
        const short8v ap0 = *(const short8v*)&Ps[(w * 16 + fr) * 72 + g * 8];
        const short8v ap1 = *(const short8v*)&Ps[(w * 16 + fr) * 72 + (4 + g) * 8];
#pragma unroll
        for (int nf = 0; nf < 4; ++nf) {
            short8v bv0 = *(const short8v*)&VTs[(nf * 16 + fr) * 72 + g * 8];
            short8v bv1 = *(const short8v*)&VTs[(nf * 16 + fr) * 72 + (4 + g) * 8];
            acc[nf] = __builtin_amdgcn_mfma_f32_16x16x32_bf16(ap0, bv0, acc[nf], 0, 0, 0);
            acc[nf] = __builtin_amdgcn_mfma_f32_16x16x32_bf16(ap1, bv1, acc[nf], 0, 0, 0);
        }
    }

#pragma unroll
    for (int reg = 0; reg < 4; ++reg) {
        const int i = w * 16 + g * 4 + reg;
        const float inv = 1.f / den_lds[i];
        unsigned short* dst = Af + (rowbase + i) * DMODEL + colbase;
#pragma unroll
        for (int nf = 0; nf < 4; ++nf)
            dst[nf * 16 + fr] = f2b(acc[nf][reg] * inv);
    }
}

// ---------------------------------------------------------------------------
// LayerNorm over 512: 4 rows per block (one wave each), in-place; bf16 copy.
// ---------------------------------------------------------------------------
__global__ __launch_bounds__(256) void ln_kernel(float* __restrict__ X,
                                                 const float* __restrict__ g,
                                                 const float* __restrict__ b,
                                                 unsigned short* __restrict__ Xb)
{
    const size_t row = blockIdx.x * 4 + (threadIdx.x >> 6);
    const int t = threadIdx.x & 63;
    float* xr = X + row * DMODEL;
    f32x4 x0 = *(const f32x4*)&xr[t * 4];
    f32x4 x1 = *(const f32x4*)&xr[256 + t * 4];

    float s  = x0[0] + x0[1] + x0[2] + x0[3] + x1[0] + x1[1] + x1[2] + x1[3];
    float sq = x0[0]*x0[0] + x0[1]*x0[1] + x0[2]*x0[2] + x0[3]*x0[3] +
               x1[0]*x1[0] + x1[1]*x1[1] + x1[2]*x1[2] + x1[3]*x1[3];
#pragma unroll
    for (int m = 1; m < 64; m <<= 1) {
        s  += __shfl_xor(s, m);
        sq += __shfl_xor(sq, m);
    }
    const float mu  = s * (1.f / DMODEL);
    const float var = sq * (1.f / DMODEL) - mu * mu;
    const float rr  = rsqrtf(var + LN_EPS);

    const int c0 = t * 4, c1 = 256 + t * 4;
    f32x4 g0 = *(const f32x4*)&g[c0], g1v = *(const f32x4*)&g[c1];
    f32x4 b0 = *(const f32x4*)&b[c0], b1v = *(const f32x4*)&b[c1];
    f32x4 y0, y1;
#pragma unroll
    for (int i = 0; i < 4; ++i) {
        y0[i] = (x0[i] - mu) * rr * g0[i] + b0[i];
        y1[i] = (x1[i] - mu) * rr * g1v[i] + b1v[i];
    }
    *(f32x4*)&xr[c0] = y0;
    *(f32x4*)&xr[c1] = y1;
    if (Xb) {
        unsigned short* xb = Xb + row * DMODEL;
        ushort4 u0, u1;
        u0.x = f2b(y0[0]); u0.y = f2b(y0[1]); u0.z = f2b(y0[2]); u0.w = f2b(y0[3]);
        u1.x = f2b(y1[0]); u1.y = f2b(y1[1]); u1.z = f2b(y1[2]); u1.w = f2b(y1[3]);
        *(ushort4*)&xb[c0] = u0;
        *(ushort4*)&xb[c1] = u1;
    }
}

// ---------------------------------------------------------------------------
extern "C" void kernel_launch(void* const* d_in, const int* in_sizes, int n_in,
                              void* d_out, int out_size, void* d_ws, size_t ws_size,
                              hipStream_t stream)
{
    const float* h   = (const float*)d_in[0];
    const float* Wq  = (const float*)d_in[1];
    const float* bq  = (const float*)d_in[2];
    const float* Wk  = (const float*)d_in[3];
    const float* bk  = (const float*)d_in[4];
    const float* Wv  = (const float*)d_in[5];
    const float* bv  = (const float*)d_in[6];
    const float* Wo  = (const float*)d_in[7];
    const float* bo  = (const float*)d_in[8];
    const float* W1  = (const float*)d_in[9];
    const float* b1  = (const float*)d_in[10];
    const float* W2  = (const float*)d_in[11];
    const float* b2  = (const float*)d_in[12];
    const float* g1  = (const float*)d_in[13];
    const float* be1 = (const float*)d_in[14];
    const float* g2  = (const float*)d_in[15];
    const float* be2 = (const float*)d_in[16];
    const float* gf  = (const float*)d_in[17];
    const float* bef = (const float*)d_in[18];

    float* x = (float*)d_out;                     // running activation f32 [8192,512]
    char* ws = (char*)d_ws;
    const size_t MB = 1024 * 1024;
    unsigned short* x_bf = (unsigned short*)(ws);                 // 8 MB
    unsigned short* qkv  = (unsigned short*)(ws + 8 * MB);        // q|k|v 24 MB
    unsigned short* qb   = qkv;
    unsigned short* kb   = qkv + SEGSTRIDE;
    unsigned short* vb   = qkv + 2 * (size_t)SEGSTRIDE;
    unsigned short* ab   = (unsigned short*)(ws + 32 * MB);       // 8 MB
    unsigned short* hid  = (unsigned short*)(ws + 8 * MB);        // 32 MB alias q|k|v|a
    unsigned short* KVp  = (unsigned short*)(ws + 40 * MB);       // partials bf16 8 MB
    unsigned short* KVb  = (unsigned short*)(ws + 48 * MB);       // prefix states 8 MB
    float* zp            = (float*)(ws + 56 * MB);                // 0.5 MB
    unsigned short* WTall = (unsigned short*)(ws + 57 * MB);      // 24 MB

    const int M = MROWS, D = DMODEL, DF = DFF;
    const size_t LSTR = 3 * 1024 * 1024;

    cvt_in<<<dim3(M * D / (256 * 8)), 256, 0, stream>>>(h, x, x_bf, M * D);
    for (int l = 0; l < LAYERS; ++l) {
        unsigned short* WL = WTall + (size_t)l * LSTR;
        transpose_to_bf16<<<dim3(D / 32, D / 32), 256, 0, stream>>>(Wq + (size_t)l * D * D, WL, D, D);
        transpose_to_bf16<<<dim3(D / 32, D / 32), 256, 0, stream>>>(Wk + (size_t)l * D * D, WL + 262144, D, D);
        transpose_to_bf16<<<dim3(D / 32, D / 32), 256, 0, stream>>>(Wv + (size_t)l * D * D, WL + 524288, D, D);
        transpose_to_bf16<<<dim3(D / 32, D / 32), 256, 0, stream>>>(Wo + (size_t)l * D * D, WL + 786432, D, D);
        transpose_to_bf16<<<dim3(D / 32, DF / 32), 256, 0, stream>>>(W1 + (size_t)l * D * DF, WL + 1048576, D, DF);
        transpose_to_bf16<<<dim3(DF / 32, D / 32), 256, 0, stream>>>(W2 + (size_t)l * DF * D, WL + 2097152, DF, D);
    }

    for (int l = 0; l < LAYERS; ++l) {
        unsigned short* WL = WTall + (size_t)l * LSTR;
        const unsigned short* WqkvT = WL;            // [1536][512]
        const unsigned short* WoT   = WL + 786432;   // [512][512]
        const unsigned short* W1T   = WL + 1048576;  // [2048][512]
        const unsigned short* W2T   = WL + 2097152;  // [512][2048]

        // fused q|k|v projection: 256^2 tile, 8 waves
        gemm_mfma<256, 256, 512, 2, 4, 3, false, false, true>
            <<<dim3(M / 256, 1536 / 256), 512, 0, stream>>>(
            x_bf, WqkvT, bq + (size_t)l * D, bk + (size_t)l * D, bv + (size_t)l * D,
            nullptr, qkv, M, 1536, D);

        attn_stage1<<<dim3(NCHUNK, NH, NB), 256, 0, stream>>>(kb, vb, KVp, zp);
        attn_stage2<<<dim3(NB * NH, 16), 256, 0, stream>>>(KVp, KVb, zp);
        attn_stage3<<<dim3(NCHUNK, NH, NB), 256, 0, stream>>>(qb, kb, vb, KVb, zp, ab);

        // out projection + residual into x (f32): 128^2 tile, 4 waves
        gemm_mfma<128, 128, 256, 2, 2, 0, true, true, false>
            <<<dim3(M / 128, D / 128), 256, 0, stream>>>(
            ab, WoT, bo + (size_t)l * D, nullptr, nullptr, x, nullptr, M, D, D);
        ln_kernel<<<dim3(M / 4), 256, 0, stream>>>(x, g1 + (size_t)l * D, be1 + (size_t)l * D, x_bf);

        // FFN
        gemm_mfma<256, 256, 512, 2, 4, 2, false, false, true>
            <<<dim3(M / 256, DF / 256), 512, 0, stream>>>(
            x_bf, W1T, b1 + (size_t)l * DF, nullptr, nullptr, nullptr, hid, M, DF, D);
        gemm_mfma<128, 128, 256, 2, 2, 0, true, true, false>
            <<<dim3(M / 128, D / 128), 256, 0, stream>>>(
            hid, W2T, b2 + (size_t)l * D, nullptr, nullptr, x, nullptr, M, D, DF);
        ln_kernel<<<dim3(M / 4), 256, 0, stream>>>(x, g2 + (size_t)l * D, be2 + (size_t)l * D, x_bf);
    }

    ln_kernel<<<dim3(M / 4), 256, 0, stream>>>(x, gf, bef, nullptr);
}

// Round 8
// 660.550 us; speedup vs baseline: 1.2129x; 1.1110x over previous
//
#include <hip/hip_runtime.h>
#include <hip/hip_bf16.h>
#include <math.h>

#define LAYERS 4
#define DMODEL 512
#define NH 8
#define DH 64
#define DFF 2048
#define NB 4
#define S_LEN 2048
#define MROWS 8192
#define CHUNK 64
#define NCHUNK 32            // S_LEN / CHUNK
#define ATT_EPS 1e-6f
#define LN_EPS 1e-5f
#define SEGSTRIDE (MROWS * DMODEL)   // 4194304 elems per q/k/v segment

typedef __attribute__((ext_vector_type(8))) short short8v;   // 8 bf16
typedef __attribute__((ext_vector_type(4))) float f32x4;

__device__ __forceinline__ float b2f(unsigned short u) {
    union { float f; unsigned u; } c; c.u = ((unsigned)u) << 16; return c.f;
}
__device__ __forceinline__ unsigned short f2b(float f) {
    union { float f; unsigned u; } c; c.f = f;
    unsigned r = c.u + 0x7FFFu + ((c.u >> 16) & 1u);
    return (unsigned short)(r >> 16);
}
__device__ __forceinline__ void gload16(const void* g, void* l) {
    __builtin_amdgcn_global_load_lds(
        (const __attribute__((address_space(1))) void*)g,
        (__attribute__((address_space(3))) void*)l, 16, 0, 0);
}
__device__ __forceinline__ float elu1f(float v) {
    return (v > 0.f) ? (v + 1.f) : __expf(v);
}
__device__ __forceinline__ float geluf(float v) {
    float u = 0.7978845608028654f * v * (1.f + 0.044715f * v * v);
    float th = 1.f - 2.f / (1.f + __expf(2.f * u));
    return 0.5f * v * (1.f + th);
}

// ---------------------------------------------------------------------------
// bf16 MFMA GEMM: 128x128 tile, BK=64, 8 waves (2x4 -> 64x32 each), 2x32KB
// LDS buffers -> 2 blocks/CU = 16 waves/CU (4/SIMD) for inter-wave overlap.
// Depth-1 counted vmcnt(4); 12 ds_reads split into 2 lgkmcnt-gated MFMA
// halves; 8-slot XOR row swizzle (2-way max = free).
// KSPLIT: blockIdx.z splits K; ATOMIC epilogue accumulates via atomicAdd.
// ---------------------------------------------------------------------------
template <int ACT, bool ACCUM, bool ATOMIC, bool WF32, bool WBF16, int KSPLIT>
__global__ __launch_bounds__(512, 4) void gemm8(
    const unsigned short* __restrict__ A,
    const unsigned short* __restrict__ WT,
    const float* __restrict__ b0, const float* __restrict__ b1,
    const float* __restrict__ b2,
    float* __restrict__ C32, unsigned short* __restrict__ Cbf,
    int M, int N, int K)
{
    __shared__ short S[2][16384];   // [A 128x64 | B 128x64] swizzled, 32KB/buf

    const int t = threadIdx.x;
    const int m0 = blockIdx.x * 128, n0 = blockIdx.y * 128;
    const int kz = (KSPLIT > 1) ? blockIdx.z : 0;
    const int Kc = K / KSPLIT;          // K per block
    const int kbeg = kz * Kc;
    const int lane = t & 63, wid = t >> 6;
    const int wm = (wid >> 2) * 64;     // 2 M-groups
    const int wn = (wid & 3) * 32;      // 4 N-groups
    const int fr = lane & 15, kg = lane >> 4;

    // staging: 16B-unit u (0..1023 per operand): row=u>>3, phys slot=u&7,
    // logical slot = phys ^ (row&7). Linear LDS dest, swizzled global source.
    const unsigned short* gsrc[4];
    int ldso[4];
#pragma unroll
    for (int r = 0; r < 4; ++r) {
        const int u = (r & 1) ? (t + 512) : t;
        const bool isA = (r < 2);
        const int row = u >> 3, sp = u & 7, sl = sp ^ (row & 7);
        gsrc[r] = (isA ? A + (size_t)(m0 + row) * K
                       : WT + (size_t)(n0 + row) * K) + kbeg + sl * 8;
        ldso[r] = (isA ? 0 : 8192) + u * 8;
    }

    // fragment read offsets: row R, k-half h, slot (h*4+kg)^(R&7)
    int aoff[2][4], boff[2][2];
#pragma unroll
    for (int h = 0; h < 2; ++h) {
#pragma unroll
        for (int m = 0; m < 4; ++m) {
            const int R = wm + m * 16 + fr;
            aoff[h][m] = R * 64 + (((h * 4 + kg) ^ (R & 7)) * 8);
        }
#pragma unroll
        for (int n = 0; n < 2; ++n) {
            const int R = wn + n * 16 + fr;
            boff[h][n] = 8192 + R * 64 + (((h * 4 + kg) ^ (R & 7)) * 8);
        }
    }

    f32x4 acc[4][2];
#pragma unroll
    for (int m = 0; m < 4; ++m)
#pragma unroll
        for (int n = 0; n < 2; ++n) acc[m][n] = (f32x4){0.f, 0.f, 0.f, 0.f};

#define STAGE(b, kt) do { _Pragma("unroll")                                  \
    for (int r = 0; r < 4; ++r)                                              \
        gload16(gsrc[r] + (size_t)(kt) * 64, &S[b][ldso[r]]); } while (0)

    const int NT = Kc >> 6;
    STAGE(0, 0);

    for (int td = 0; td < NT; ++td) {
        const int b = td & 1;
        if (td + 1 < NT) {
            STAGE(b ^ 1, td + 1);
            __builtin_amdgcn_sched_barrier(0);
            asm volatile("s_waitcnt vmcnt(4)");   // tile td landed
        } else {
            __builtin_amdgcn_sched_barrier(0);
            asm volatile("s_waitcnt vmcnt(0)");
        }
        __builtin_amdgcn_sched_barrier(0);
        __builtin_amdgcn_s_barrier();
        __builtin_amdgcn_sched_barrier(0);

        short8v a0[4], b0f[2], a1[4], b1f[2];
#pragma unroll
        for (int m = 0; m < 4; ++m) a0[m] = *(const short8v*)&S[b][aoff[0][m]];
#pragma unroll
        for (int n = 0; n < 2; ++n) b0f[n] = *(const short8v*)&S[b][boff[0][n]];
#pragma unroll
        for (int m = 0; m < 4; ++m) a1[m] = *(const short8v*)&S[b][aoff[1][m]];
#pragma unroll
        for (int n = 0; n < 2; ++n) b1f[n] = *(const short8v*)&S[b][boff[1][n]];

        asm volatile("s_waitcnt lgkmcnt(6)");   // half-0 frags ready
        __builtin_amdgcn_sched_barrier(0);
        __builtin_amdgcn_s_setprio(1);
#pragma unroll
        for (int m = 0; m < 4; ++m)
#pragma unroll
            for (int n = 0; n < 2; ++n)
                acc[m][n] = __builtin_amdgcn_mfma_f32_16x16x32_bf16(
                    a0[m], b0f[n], acc[m][n], 0, 0, 0);
        __builtin_amdgcn_s_setprio(0);

        asm volatile("s_waitcnt lgkmcnt(0)");   // half-1 frags ready
        __builtin_amdgcn_sched_barrier(0);
        __builtin_amdgcn_s_setprio(1);
#pragma unroll
        for (int m = 0; m < 4; ++m)
#pragma unroll
            for (int n = 0; n < 2; ++n)
                acc[m][n] = __builtin_amdgcn_mfma_f32_16x16x32_bf16(
                    a1[m], b1f[n], acc[m][n], 0, 0, 0);
        __builtin_amdgcn_s_setprio(0);

        __builtin_amdgcn_sched_barrier(0);
        __builtin_amdgcn_s_barrier();   // protect buf b before restage
    }
#undef STAGE

    // epilogue
    const int seg = (ACT == 3) ? (n0 >> 9) : 0;
    const float* bias = (ACT == 3) ? (seg == 0 ? b0 : (seg == 1 ? b1 : b2)) : b0;
    float bv[2];
#pragma unroll
    for (int n = 0; n < 2; ++n) {
        const int col = n0 + wn + n * 16 + fr;
        bv[n] = bias[(ACT == 3) ? (col - seg * 512) : col];
    }
    if (KSPLIT > 1 && kz != 0) { bv[0] = 0.f; bv[1] = 0.f; }

#pragma unroll
    for (int m = 0; m < 4; ++m)
#pragma unroll
        for (int n = 0; n < 2; ++n)
#pragma unroll
            for (int j = 0; j < 4; ++j) {
                const int row = m0 + wm + m * 16 + (lane >> 4) * 4 + j;
                const int col = n0 + wn + n * 16 + fr;
                float v = acc[m][n][j] + bv[n];
                if (ACCUM) v += C32[(size_t)row * N + col];
                if (ACT == 1) v = elu1f(v);
                else if (ACT == 2) v = geluf(v);
                else if (ACT == 3) { if (seg < 2) v = elu1f(v); }
                if (ATOMIC) {
                    atomicAdd(&C32[(size_t)row * N + col], v);
                } else {
                    if (WF32) C32[(size_t)row * N + col] = v;
                }
                if (WBF16) {
                    if (ACT == 3)
                        Cbf[(size_t)seg * SEGSTRIDE + (size_t)row * 512 + (col - seg * 512)] = f2b(v);
                    else
                        Cbf[(size_t)row * N + col] = f2b(v);
                }
            }
}

// ---------------------------------------------------------------------------
// Weight transpose + bf16
// ---------------------------------------------------------------------------
__global__ __launch_bounds__(256) void transpose_to_bf16(
    const float* __restrict__ W, unsigned short* __restrict__ WT, int K, int N)
{
    __shared__ float tile[32][33];
    const int k0 = blockIdx.x * 32, n0 = blockIdx.y * 32;
    const int tx = threadIdx.x & 31, ty = threadIdx.x >> 5;
#pragma unroll
    for (int i = ty; i < 32; i += 8)
        tile[i][tx] = W[(size_t)(k0 + i) * N + n0 + tx];
    __syncthreads();
#pragma unroll
    for (int i = ty; i < 32; i += 8)
        WT[(size_t)(n0 + i) * K + k0 + tx] = f2b(tile[tx][i]);
}

__global__ __launch_bounds__(256) void cvt_in(
    const float* __restrict__ h, float* __restrict__ x,
    unsigned short* __restrict__ xb, int n)
{
    const int i = (blockIdx.x * 256 + threadIdx.x) * 8;
    if (i >= n) return;
    f32x4 a = *(const f32x4*)(h + i);
    f32x4 b = *(const f32x4*)(h + i + 4);
    *(f32x4*)(x + i) = a;
    *(f32x4*)(x + i + 4) = b;
    short8v p;
    p[0] = f2b(a[0]); p[1] = f2b(a[1]); p[2] = f2b(a[2]); p[3] = f2b(a[3]);
    p[4] = f2b(b[0]); p[5] = f2b(b[1]); p[6] = f2b(b[2]); p[7] = f2b(b[3]);
    *(short8v*)(xb + i) = p;
}

// swizzled 64x64 bf16 tile access: logical (row, sl) -> shorts offset
__device__ __forceinline__ int swzo(int row, int sl) {
    return row * 64 + ((sl ^ (row & 7)) << 3);
}

// ---------------------------------------------------------------------------
// Attention stage 1 (MFMA): per (b,h,chunk) KVt[e][d] = sum_j V[j][e]*K[j][d]
// ---------------------------------------------------------------------------
__global__ __launch_bounds__(256) void attn_stage1(
    const unsigned short* __restrict__ Kf, const unsigned short* __restrict__ Vf,
    unsigned short* __restrict__ KVp, float* __restrict__ zp)
{
    const int c = blockIdx.x, hh = blockIdx.y, bb = blockIdx.z;
    const int t = threadIdx.x;
    const int lane = t & 63, w = t >> 6;
    const int fr = lane & 15, g = lane >> 4;

    __shared__ unsigned short KTs[64 * 72];
    __shared__ unsigned short VTs[64 * 72];

    const size_t rowbase = (size_t)(bb * S_LEN + c * CHUNK);
    const int colbase = hh * DH;

    {
        const int r = lane, cs = w * 16;
        const unsigned short* kp = Kf + (rowbase + r) * DMODEL + colbase + cs;
        const unsigned short* vp = Vf + (rowbase + r) * DMODEL + colbase + cs;
        short8v k0 = *(const short8v*)kp, k1 = *(const short8v*)(kp + 8);
        short8v v0 = *(const short8v*)vp, v1 = *(const short8v*)(vp + 8);
#pragma unroll
        for (int i = 0; i < 8; ++i) {
            KTs[(cs + i) * 72 + r]     = (unsigned short)k0[i];
            KTs[(cs + 8 + i) * 72 + r] = (unsigned short)k1[i];
            VTs[(cs + i) * 72 + r]     = (unsigned short)v0[i];
            VTs[(cs + 8 + i) * 72 + r] = (unsigned short)v1[i];
        }
    }
    __syncthreads();

    f32x4 cacc[4];
#pragma unroll
    for (int nf = 0; nf < 4; ++nf) cacc[nf] = (f32x4){0.f, 0.f, 0.f, 0.f};

    const short8v a0 = *(const short8v*)&VTs[(w * 16 + fr) * 72 + g * 8];
    const short8v a1 = *(const short8v*)&VTs[(w * 16 + fr) * 72 + (4 + g) * 8];
#pragma unroll
    for (int nf = 0; nf < 4; ++nf) {
        short8v bq0 = *(const short8v*)&KTs[(nf * 16 + fr) * 72 + g * 8];
        short8v bq1 = *(const short8v*)&KTs[(nf * 16 + fr) * 72 + (4 + g) * 8];
        cacc[nf] = __builtin_amdgcn_mfma_f32_16x16x32_bf16(a0, bq0, cacc[nf], 0, 0, 0);
        cacc[nf] = __builtin_amdgcn_mfma_f32_16x16x32_bf16(a1, bq1, cacc[nf], 0, 0, 0);
    }

    const size_t base = ((size_t)(bb * NH + hh) * NCHUNK + c) * (DH * DH);
#pragma unroll
    for (int nf = 0; nf < 4; ++nf)
#pragma unroll
        for (int reg = 0; reg < 4; ++reg) {
            const int e = w * 16 + g * 4 + reg;
            const int d = nf * 16 + fr;
            KVp[base + e * 64 + d] = f2b(cacc[nf][reg]);
        }

    if (t < 64) {
        float s = 0.f;
#pragma unroll
        for (int sl = 0; sl < 8; ++sl) {
            short8v kv = *(const short8v*)&KTs[t * 72 + sl * 8];
#pragma unroll
            for (int i = 0; i < 8; ++i) s += b2f((unsigned short)kv[i]);
        }
        zp[((size_t)(bb * NH + hh) * NCHUNK + c) * DH + t] = s;
    }
}

// ---------------------------------------------------------------------------
// Attention stage 2: exclusive prefix over 32 chunk states per (b,h)
// ---------------------------------------------------------------------------
__global__ __launch_bounds__(256) void attn_stage2(
    const unsigned short* __restrict__ KVp, unsigned short* __restrict__ KVb,
    float* __restrict__ zp)
{
    const int bh = blockIdx.x;
    const int e = blockIdx.y * 256 + threadIdx.x;
    const size_t base = (size_t)bh * NCHUNK * (DH * DH) + e;
    float run = 0.f;
#pragma unroll 4
    for (int c = 0; c < NCHUNK; ++c) {
        const float tmp = b2f(KVp[base + (size_t)c * (DH * DH)]);
        KVb[base + (size_t)c * (DH * DH)] = f2b(run);
        run += tmp;
    }
    if (blockIdx.y == 0 && threadIdx.x < DH) {
        float rz = 0.f;
        const size_t zb = (size_t)bh * NCHUNK * DH + threadIdx.x;
#pragma unroll 4
        for (int c = 0; c < NCHUNK; ++c) {
            const float tmp = zp[zb + c * DH];
            zp[zb + c * DH] = rz;
            rz += tmp;
        }
    }
}

// ---------------------------------------------------------------------------
// Attention stage 3 (MFMA)
// ---------------------------------------------------------------------------
__global__ __launch_bounds__(256) void attn_stage3(
    const unsigned short* __restrict__ Qf, const unsigned short* __restrict__ Kf,
    const unsigned short* __restrict__ Vf, const unsigned short* __restrict__ KVb,
    const float* __restrict__ zp, unsigned short* __restrict__ Af)
{
    const int c = blockIdx.x, hh = blockIdx.y, bb = blockIdx.z;
    const int t = threadIdx.x;
    const int lane = t & 63, w = t >> 6;
    const int fr = lane & 15, g = lane >> 4;

    __shared__ unsigned short Qs[4096];
    __shared__ unsigned short Ks[4096];
    __shared__ unsigned short KVts[4096];
    __shared__ unsigned short VTs[64 * 72];
    __shared__ unsigned short Ps[64 * 72];
    __shared__ float zsh[DH];
    __shared__ float den_lds[64];

    const size_t rowbase = (size_t)(bb * S_LEN + c * CHUNK);
    const int colbase = hh * DH;
    const size_t kvbase = ((size_t)(bb * NH + hh) * NCHUNK + c) * (DH * DH);

#pragma unroll
    for (int iss = 0; iss < 2; ++iss) {
        const int u = iss * 256 + t, row = u >> 3, sl = u & 7;
        const int ssl = (sl ^ (row & 7)) * 8;
        gload16(Qf + (rowbase + row) * DMODEL + colbase + ssl, &Qs[(size_t)u * 8]);
        gload16(Kf + (rowbase + row) * DMODEL + colbase + ssl, &Ks[(size_t)u * 8]);
        gload16(KVb + kvbase + row * 64 + ssl, &KVts[(size_t)u * 8]);
    }
    {
        const int r = lane, cs = w * 16;
        const unsigned short* vp = Vf + (rowbase + r) * DMODEL + colbase + cs;
        short8v v0 = *(const short8v*)vp, v1 = *(const short8v*)(vp + 8);
#pragma unroll
        for (int i = 0; i < 8; ++i) {
            VTs[(cs + i) * 72 + r]     = (unsigned short)v0[i];
            VTs[(cs + 8 + i) * 72 + r] = (unsigned short)v1[i];
        }
    }
    if (t < DH) zsh[t] = zp[((size_t)(bb * NH + hh) * NCHUNK + c) * DH + t];
    __syncthreads();

    f32x4 c1[4];
#pragma unroll
    for (int mf = 0; mf < 4; ++mf) c1[mf] = (f32x4){0.f, 0.f, 0.f, 0.f};
    {
        const short8v bq0 = *(const short8v*)&Qs[swzo(w * 16 + fr, g)];
        const short8v bq1 = *(const short8v*)&Qs[swzo(w * 16 + fr, 4 + g)];
#pragma unroll
        for (int mf = 0; mf < 4; ++mf) {
            short8v ak0 = *(const short8v*)&Ks[swzo(mf * 16 + fr, g)];
            short8v ak1 = *(const short8v*)&Ks[swzo(mf * 16 + fr, 4 + g)];
            c1[mf] = __builtin_amdgcn_mfma_f32_16x16x32_bf16(ak0, bq0, c1[mf], 0, 0, 0);
            c1[mf] = __builtin_amdgcn_mfma_f32_16x16x32_bf16(ak1, bq1, c1[mf], 0, 0, 0);
        }
    }

    const int i_my = w * 16 + fr;
    float dint = 0.f;
#pragma unroll
    for (int mf = 0; mf < 4; ++mf)
#pragma unroll
        for (int reg = 0; reg < 4; ++reg) {
            const int j = mf * 16 + g * 4 + reg;
            const float v = (j <= i_my) ? c1[mf][reg] : 0.f;
            dint += v;
            Ps[i_my * 72 + j] = f2b(v);
        }
    dint += __shfl_xor(dint, 16);
    dint += __shfl_xor(dint, 32);

    float dpre = 0.f;
#pragma unroll
    for (int sl = 0; sl < 8; ++sl) {
        short8v qv = *(const short8v*)&Qs[swzo(i_my, sl)];
#pragma unroll
        for (int e = 0; e < 8; ++e) dpre += b2f((unsigned short)qv[e]) * zsh[sl * 8 + e];
    }
    if (g == 0) den_lds[i_my] = dpre + dint + ATT_EPS;

    f32x4 acc[4];
#pragma unroll
    for (int nf = 0; nf < 4; ++nf) acc[nf] = (f32x4){0.f, 0.f, 0.f, 0.f};
    {
        const short8v aq0 = *(const short8v*)&Qs[swzo(w * 16 + fr, g)];
        const short8v aq1 = *(const short8v*)&Qs[swzo(w * 16 + fr, 4 + g)];
#pragma unroll
        for (int nf = 0; nf < 4; ++nf) {
            short8v bkv0 = *(const short8v*)&KVts[swzo(nf * 16 + fr, g)];
            short8v bkv1 = *(const short8v*)&KVts[swzo(nf * 16 + fr, 4 + g)];
            acc[nf] = __builtin_amdgcn_mfma_f32_16x16x32_bf16(aq0, bkv0, acc[nf], 0, 0, 0);
            acc[nf] = __builtin_amdgcn_mfma_f32_16x16x32_bf16(aq1, bkv1, acc[nf], 0, 0, 0);
        }
        const short8v ap0 = *(const short8v*)&Ps[(w * 16 + fr) * 72 + g * 8];
        const short8v ap1 = *(const short8v*)&Ps[(w * 16 + fr) * 72 + (4 + g) * 8];
#pragma unroll
        for (int nf = 0; nf < 4; ++nf) {
            short8v bv0 = *(const short8v*)&VTs[(nf * 16 + fr) * 72 + g * 8];
            short8v bv1 = *(const short8v*)&VTs[(nf * 16 + fr) * 72 + (4 + g) * 8];
            acc[nf] = __builtin_amdgcn_mfma_f32_16x16x32_bf16(ap0, bv0, acc[nf], 0, 0, 0);
            acc[nf] = __builtin_amdgcn_mfma_f32_16x16x32_bf16(ap1, bv1, acc[nf], 0, 0, 0);
        }
    }

#pragma unroll
    for (int reg = 0; reg < 4; ++reg) {
        const int i = w * 16 + g * 4 + reg;
        const float inv = 1.f / den_lds[i];
        unsigned short* dst = Af + (rowbase + i) * DMODEL + colbase;
#pragma unroll
        for (int nf = 0; nf < 4; ++nf)
            dst[nf * 16 + fr] = f2b(acc[nf][reg] * inv);
    }
}

// ---------------------------------------------------------------------------
// LayerNorm over 512: 4 rows per block (one wave each), in-place; bf16 copy.
// ---------------------------------------------------------------------------
__global__ __launch_bounds__(256) void ln_kernel(float* __restrict__ X,
                                                 const float* __restrict__ g,
                                                 const float* __restrict__ b,
                                                 unsigned short* __restrict__ Xb)
{
    const size_t row = blockIdx.x * 4 + (threadIdx.x >> 6);
    const int t = threadIdx.x & 63;
    float* xr = X + row * DMODEL;
    f32x4 x0 = *(const f32x4*)&xr[t * 4];
    f32x4 x1 = *(const f32x4*)&xr[256 + t * 4];

    float s  = x0[0] + x0[1] + x0[2] + x0[3] + x1[0] + x1[1] + x1[2] + x1[3];
    float sq = x0[0]*x0[0] + x0[1]*x0[1] + x0[2]*x0[2] + x0[3]*x0[3] +
               x1[0]*x1[0] + x1[1]*x1[1] + x1[2]*x1[2] + x1[3]*x1[3];
#pragma unroll
    for (int m = 1; m < 64; m <<= 1) {
        s  += __shfl_xor(s, m);
        sq += __shfl_xor(sq, m);
    }
    const float mu  = s * (1.f / DMODEL);
    const float var = sq * (1.f / DMODEL) - mu * mu;
    const float rr  = rsqrtf(var + LN_EPS);

    const int c0 = t * 4, c1 = 256 + t * 4;
    f32x4 g0 = *(const f32x4*)&g[c0], g1v = *(const f32x4*)&g[c1];
    f32x4 b0 = *(const f32x4*)&b[c0], b1v = *(const f32x4*)&b[c1];
    f32x4 y0, y1;
#pragma unroll
    for (int i = 0; i < 4; ++i) {
        y0[i] = (x0[i] - mu) * rr * g0[i] + b0[i];
        y1[i] = (x1[i] - mu) * rr * g1v[i] + b1v[i];
    }
    *(f32x4*)&xr[c0] = y0;
    *(f32x4*)&xr[c1] = y1;
    if (Xb) {
        unsigned short* xb = Xb + row * DMODEL;
        ushort4 u0, u1;
        u0.x = f2b(y0[0]); u0.y = f2b(y0[1]); u0.z = f2b(y0[2]); u0.w = f2b(y0[3]);
        u1.x = f2b(y1[0]); u1.y = f2b(y1[1]); u1.z = f2b(y1[2]); u1.w = f2b(y1[3]);
        *(ushort4*)&xb[c0] = u0;
        *(ushort4*)&xb[c1] = u1;
    }
}

// ---------------------------------------------------------------------------
extern "C" void kernel_launch(void* const* d_in, const int* in_sizes, int n_in,
                              void* d_out, int out_size, void* d_ws, size_t ws_size,
                              hipStream_t stream)
{
    const float* h   = (const float*)d_in[0];
    const float* Wq  = (const float*)d_in[1];
    const float* bq  = (const float*)d_in[2];
    const float* Wk  = (const float*)d_in[3];
    const float* bk  = (const float*)d_in[4];
    const float* Wv  = (const float*)d_in[5];
    const float* bv  = (const float*)d_in[6];
    const float* Wo  = (const float*)d_in[7];
    const float* bo  = (const float*)d_in[8];
    const float* W1  = (const float*)d_in[9];
    const float* b1  = (const float*)d_in[10];
    const float* W2  = (const float*)d_in[11];
    const float* b2  = (const float*)d_in[12];
    const float* g1  = (const float*)d_in[13];
    const float* be1 = (const float*)d_in[14];
    const float* g2  = (const float*)d_in[15];
    const float* be2 = (const float*)d_in[16];
    const float* gf  = (const float*)d_in[17];
    const float* bef = (const float*)d_in[18];

    float* x = (float*)d_out;                     // running activation f32 [8192,512]
    char* ws = (char*)d_ws;
    const size_t MB = 1024 * 1024;
    unsigned short* x_bf = (unsigned short*)(ws);                 // 8 MB
    unsigned short* qkv  = (unsigned short*)(ws + 8 * MB);        // q|k|v 24 MB
    unsigned short* qb   = qkv;
    unsigned short* kb   = qkv + SEGSTRIDE;
    unsigned short* vb   = qkv + 2 * (size_t)SEGSTRIDE;
    unsigned short* ab   = (unsigned short*)(ws + 32 * MB);       // 8 MB
    unsigned short* hid  = (unsigned short*)(ws + 8 * MB);        // 32 MB alias q|k|v|a
    unsigned short* KVp  = (unsigned short*)(ws + 40 * MB);       // partials bf16 8 MB
    unsigned short* KVb  = (unsigned short*)(ws + 48 * MB);       // prefix states 8 MB
    float* zp            = (float*)(ws + 56 * MB);                // 0.5 MB
    unsigned short* WTall = (unsigned short*)(ws + 57 * MB);      // 24 MB

    const int M = MROWS, D = DMODEL, DF = DFF;
    const size_t LSTR = 3 * 1024 * 1024;

    cvt_in<<<dim3(M * D / (256 * 8)), 256, 0, stream>>>(h, x, x_bf, M * D);
    for (int l = 0; l < LAYERS; ++l) {
        unsigned short* WL = WTall + (size_t)l * LSTR;
        transpose_to_bf16<<<dim3(D / 32, D / 32), 256, 0, stream>>>(Wq + (size_t)l * D * D, WL, D, D);
        transpose_to_bf16<<<dim3(D / 32, D / 32), 256, 0, stream>>>(Wk + (size_t)l * D * D, WL + 262144, D, D);
        transpose_to_bf16<<<dim3(D / 32, D / 32), 256, 0, stream>>>(Wv + (size_t)l * D * D, WL + 524288, D, D);
        transpose_to_bf16<<<dim3(D / 32, D / 32), 256, 0, stream>>>(Wo + (size_t)l * D * D, WL + 786432, D, D);
        transpose_to_bf16<<<dim3(D / 32, DF / 32), 256, 0, stream>>>(W1 + (size_t)l * D * DF, WL + 1048576, D, DF);
        transpose_to_bf16<<<dim3(DF / 32, D / 32), 256, 0, stream>>>(W2 + (size_t)l * DF * D, WL + 2097152, DF, D);
    }

    for (int l = 0; l < LAYERS; ++l) {
        unsigned short* WL = WTall + (size_t)l * LSTR;
        const unsigned short* WqkvT = WL;            // [1536][512]
        const unsigned short* WoT   = WL + 786432;   // [512][512]
        const unsigned short* W1T   = WL + 1048576;  // [2048][512]
        const unsigned short* W2T   = WL + 2097152;  // [512][2048]

        // fused q|k|v projection (elu+1 on q,k), bf16 out: 768 blocks
        gemm8<3, false, false, false, true, 1>
            <<<dim3(M / 128, 1536 / 128), 512, 0, stream>>>(
            x_bf, WqkvT, bq + (size_t)l * D, bk + (size_t)l * D, bv + (size_t)l * D,
            nullptr, qkv, M, 1536, D);

        attn_stage1<<<dim3(NCHUNK, NH, NB), 256, 0, stream>>>(kb, vb, KVp, zp);
        attn_stage2<<<dim3(NB * NH, 16), 256, 0, stream>>>(KVp, KVb, zp);
        attn_stage3<<<dim3(NCHUNK, NH, NB), 256, 0, stream>>>(qb, kb, vb, KVb, zp, ab);

        // out projection + residual into x (f32): 256 blocks
        gemm8<0, true, false, true, false, 1>
            <<<dim3(M / 128, D / 128), 512, 0, stream>>>(
            ab, WoT, bo + (size_t)l * D, nullptr, nullptr, x, nullptr, M, D, D);
        ln_kernel<<<dim3(M / 4), 256, 0, stream>>>(x, g1 + (size_t)l * D, be1 + (size_t)l * D, x_bf);

        // FFN: W1 1024 blocks; W2 split-K=2 atomic accumulate into x (512 blocks)
        gemm8<2, false, false, false, true, 1>
            <<<dim3(M / 128, DF / 128), 512, 0, stream>>>(
            x_bf, W1T, b1 + (size_t)l * DF, nullptr, nullptr, nullptr, hid, M, DF, D);
        gemm8<0, false, true, false, false, 2>
            <<<dim3(M / 128, D / 128, 2), 512, 0, stream>>>(
            hid, W2T, b2 + (size_t)l * D, nullptr, nullptr, x, nullptr, M, D, DF);
        ln_kernel<<<dim3(M / 4), 256, 0, stream>>>(x, g2 + (size_t)l * D, be2 + (size_t)l * D, x_bf);
    }

    ln_kernel<<<dim3(M / 4), 256, 0, stream>>>(x, gf, bef, nullptr);
}